// Round 7
// baseline (1268.065 us; speedup 1.0000x reference)
//
#include <hip/hip_runtime.h>

#define USER  100000
#define ITEM  50000
#define NNODE 150000
#define LAT   64
#define TXT   768
#define RP    150016          // padded rowptr length (>= NNODE+1)
#define NBUCKF 256            // row-range buckets
#define BUCKROWS 586          // ceil(NNODE / NBUCKF)
#define CHUNK 4096            // edges per partition block
#define CAPB  28              // LDS bin capacity (mean fill 16)

typedef unsigned long long u64;

// ---------------------------------------------------------------------------
// LDS-tiled GEMM + row L2-normalize:  tf = l2norm(text @ W + b)
// ---------------------------------------------------------------------------
__global__ __launch_bounds__(256) void gemm_norm_kernel(
    const float* __restrict__ text, const float* __restrict__ W,
    const float* __restrict__ b, float* __restrict__ tf, int nitems)
{
    __shared__ float As[32][68];     // [k][row], pad 68 => conflict-free b128
    __shared__ float Bs[32][64];     // [k][col]

    const int tid = threadIdx.x;
    const int tx  = tid & 15;
    const int ty  = tid >> 4;
    const int row0 = blockIdx.x * 64;

    float acc[4][4] = {};

    const int lrow = tid >> 3;             // 0..31
    const int lk4  = (tid & 7) * 4;        // 0,4,...,28

    for (int k0 = 0; k0 < TXT; k0 += 32) {
#pragma unroll
        for (int half = 0; half < 2; ++half) {
            int r = lrow + half * 32;
            int gr = row0 + r;
            if (gr >= nitems) gr = nitems - 1;
            float4 tv = *(const float4*)(text + (size_t)gr * TXT + k0 + lk4);
            As[lk4 + 0][r] = tv.x;
            As[lk4 + 1][r] = tv.y;
            As[lk4 + 2][r] = tv.z;
            As[lk4 + 3][r] = tv.w;
        }
        const float4* wf = (const float4*)(W + (size_t)k0 * LAT);
        ((float4*)Bs)[tid]       = wf[tid];
        ((float4*)Bs)[tid + 256] = wf[tid + 256];
        __syncthreads();

#pragma unroll
        for (int k = 0; k < 32; ++k) {
            float4 a4 = *(const float4*)&As[k][ty * 4];
            float4 b4 = *(const float4*)&Bs[k][tx * 4];
            float av[4] = {a4.x, a4.y, a4.z, a4.w};
            float bv[4] = {b4.x, b4.y, b4.z, b4.w};
#pragma unroll
            for (int i = 0; i < 4; ++i)
#pragma unroll
                for (int j = 0; j < 4; ++j)
                    acc[i][j] = fmaf(av[i], bv[j], acc[i][j]);
        }
        __syncthreads();
    }

    float4 b4 = *(const float4*)(b + tx * 4);
    float bv[4] = {b4.x, b4.y, b4.z, b4.w};
#pragma unroll
    for (int i = 0; i < 4; ++i) {
        float v[4];
        float ss = 0.f;
#pragma unroll
        for (int j = 0; j < 4; ++j) {
            v[j] = acc[i][j] + bv[j];
            ss = fmaf(v[j], v[j], ss);
        }
        ss += __shfl_xor(ss, 1);
        ss += __shfl_xor(ss, 2);
        ss += __shfl_xor(ss, 4);
        ss += __shfl_xor(ss, 8);
        float inv = 1.0f / fmaxf(sqrtf(ss), 1e-12f);
        int gr = row0 + ty * 4 + i;
        if (gr < nitems) {
            float4 o = {v[0] * inv, v[1] * inv, v[2] * inv, v[3] * inv};
            *(float4*)(tf + (size_t)gr * LAT + tx * 4) = o;
        }
    }
}

// ---------------------------------------------------------------------------
// Pass 1: partition edges into 256 row-range bucket lists via LDS binning.
// One reservation atomic per (bin, block) instead of one per edge.
// Record: val(32) | lrow(10) | col(18).  blockIdx.y selects matrix.
// ---------------------------------------------------------------------------
__global__ __launch_bounds__(256) void partition_kernel(
    const int* __restrict__ arows, const int* __restrict__ acols,
    const float* __restrict__ avals,
    const int* __restrict__ trows, const int* __restrict__ tcols,
    const float* __restrict__ tvals,
    u64* __restrict__ blistA, u64* __restrict__ blistT,
    int* __restrict__ bcurA, int* __restrict__ bcurT,
    int capbuck, int nedges)
{
    const int*   rows  = blockIdx.y ? trows  : arows;
    const int*   cols  = blockIdx.y ? tcols  : acols;
    const float* vals  = blockIdx.y ? tvals  : avals;
    u64*         blist = blockIdx.y ? blistT : blistA;
    int*         bcur  = blockIdx.y ? bcurT  : bcurA;

    __shared__ u64 bins[NBUCKF][CAPB];   // 57344 B
    __shared__ int bincnt[NBUCKF];

    const int tid = threadIdx.x;
    for (int i = tid; i < NBUCKF; i += 256) bincnt[i] = 0;
    __syncthreads();

    const int base = blockIdx.x * CHUNK;
    const int end  = min(nedges, base + CHUNK);
    for (int e = base + tid; e < end; e += 256) {
        int r = rows[e];
        int bk = r / BUCKROWS;
        int lr = r - bk * BUCKROWS;
        u64 pk = ((u64)__float_as_uint(vals[e]) << 32)
               | ((u64)(unsigned)lr << 18) | (unsigned)cols[e];
        int pos = atomicAdd(&bincnt[bk], 1);
        if (pos < CAPB) {
            bins[bk][pos] = pk;
        } else {                         // rare spill: direct global append
            int g = atomicAdd(&bcur[bk], 1);
            if (g < capbuck) blist[(size_t)bk * capbuck + g] = pk;
        }
    }
    __syncthreads();

    // flush: wave w handles bins [w*64, w*64+64); cnt<=28<64 -> one burst
    const int wave = tid >> 6, lane = tid & 63;
    for (int i = 0; i < 64; ++i) {
        int bk = wave * 64 + i;
        int cnt = min(bincnt[bk], CAPB);
        if (cnt == 0) continue;          // uniform (LDS broadcast)
        int gbase = 0;
        if (lane == 0) gbase = atomicAdd(&bcur[bk], cnt);
        gbase = __shfl(gbase, 0);
        if (lane < cnt) {
            int g = gbase + lane;
            if (g < capbuck) blist[(size_t)bk * capbuck + g] = bins[bk][lane];
        }
    }
}

// ---------------------------------------------------------------------------
// Pass 2: one block per bucket -> exact CSR. LDS histogram + wave scan,
// zero device atomics. Writes rowptr and compact packed records.
// ---------------------------------------------------------------------------
__global__ __launch_bounds__(256) void buildcsr_kernel(
    const u64* __restrict__ blistA, const u64* __restrict__ blistT,
    const int* __restrict__ bcurA, const int* __restrict__ bcurT,
    int* __restrict__ rpA, int* __restrict__ rpT,
    u64* __restrict__ epkA, u64* __restrict__ epkT, int capbuck)
{
    const u64* blist = blockIdx.y ? blistT : blistA;
    const int* bcur  = blockIdx.y ? bcurT  : bcurA;
    int*       rp    = blockIdx.y ? rpT    : rpA;
    u64*       epk   = blockIdx.y ? epkT   : epkA;

    const int tid = threadIdx.x;
    const int b   = blockIdx.x;

    __shared__ int hist[BUCKROWS];
    __shared__ int rowbase[BUCKROWS];
    __shared__ int s_base;

    // base = sum_{j<b} min(bcur[j], capbuck)   (wave 0)
    if (tid < 64) {
        int partial = 0;
        for (int j = tid; j < b; j += 64) partial += min(bcur[j], capbuck);
        for (int off = 32; off >= 1; off >>= 1)
            partial += __shfl_down(partial, off);
        if (tid == 0) s_base = partial;
    }
    for (int i = tid; i < BUCKROWS; i += 256) hist[i] = 0;
    __syncthreads();

    const int n    = min(bcur[b], capbuck);
    const int base = s_base;
    const u64* bl  = blist + (size_t)b * capbuck;

    for (int e = tid; e < n; e += 256)
        atomicAdd(&hist[(int)((bl[e] >> 18) & 1023u)], 1);
    __syncthreads();

    // exclusive scan of hist -> rowbase  (wave 0, 64-wide chunks w/ carry)
    if (tid < 64) {
        int carry = 0;
        for (int ch = 0; ch * 64 < BUCKROWS; ++ch) {
            int idx = ch * 64 + tid;
            int v = (idx < BUCKROWS) ? hist[idx] : 0;
            int s = v;
            for (int off = 1; off < 64; off <<= 1) {
                int t = __shfl_up(s, off);
                if (tid >= off) s += t;
            }
            if (idx < BUCKROWS) rowbase[idx] = s - v + carry;
            carry += __shfl(s, 63);
        }
    }
    __syncthreads();

    // rowptr for this bucket's rows
    const int nrows = min(BUCKROWS, NNODE - b * BUCKROWS);
    for (int i = tid; i < nrows; i += 256)
        rp[b * BUCKROWS + i] = base + rowbase[i];
    if (b == NBUCKF - 1 && tid == 0) rp[NNODE] = base + n;

    // re-zero hist as placement cursor
    for (int i = tid; i < BUCKROWS; i += 256) hist[i] = 0;
    __syncthreads();

    for (int e = tid; e < n; e += 256) {
        u64 pk = bl[e];
        int lr = (int)((pk >> 18) & 1023u);
        int k  = atomicAdd(&hist[lr], 1);          // LDS atomic
        epk[(size_t)base + rowbase[lr] + k] =
            (pk & 0xFFFFFFFF00000000ULL) | (pk & 0x3FFFFULL);
    }
}

// ---------------------------------------------------------------------------
// Exact-CSR gather SpMM, one row/wave, 4 edge-groups x 16 lanes x float4:
//   res[r] = scale * sum_e val*x[col] + add1[r] + add2[r]
//   if (out)  out[r]  = res
//   if (out2) out2[r] = res (assign) or out2[r] += res
// ---------------------------------------------------------------------------
__global__ __launch_bounds__(256) void spmm_kernel(
    const int* __restrict__ rowptr, const u64* __restrict__ epk,
    const float* __restrict__ xu, const float* __restrict__ xi,
    float scale, const float* __restrict__ add1, const float* __restrict__ add2,
    float* __restrict__ out, float* __restrict__ out2, int out2_assign, int n)
{
    int r = blockIdx.x * 4 + (threadIdx.x >> 6);
    if (r >= n) return;
    int lane = threadIdx.x & 63;
    int g = lane >> 4;
    int l = lane & 15;

    int start = rowptr[r], end = rowptr[r + 1];
    float4 acc = {0.f, 0.f, 0.f, 0.f};
    for (int e = start + g; e < end; e += 4) {
        u64 pk = epk[e];
        int c   = (int)(unsigned)(pk & 0xffffffffu);
        float v = __uint_as_float((unsigned)(pk >> 32));
        const float* x = (c < USER) ? (xu + (size_t)c * LAT)
                                    : (xi + (size_t)(c - USER) * LAT);
        float4 xv = *(const float4*)(x + 4 * l);
        acc.x = fmaf(v, xv.x, acc.x);
        acc.y = fmaf(v, xv.y, acc.y);
        acc.z = fmaf(v, xv.z, acc.z);
        acc.w = fmaf(v, xv.w, acc.w);
    }
#pragma unroll
    for (int off = 16; off <= 32; off <<= 1) {
        acc.x += __shfl_xor(acc.x, off);
        acc.y += __shfl_xor(acc.y, off);
        acc.z += __shfl_xor(acc.z, off);
        acc.w += __shfl_xor(acc.w, off);
    }
    if (g == 0) {
        size_t idx = (size_t)r * LAT + 4 * l;
        float4 res = {scale * acc.x, scale * acc.y, scale * acc.z, scale * acc.w};
        if (add1) {
            float4 a = *(const float4*)(add1 + idx);
            res.x += a.x; res.y += a.y; res.z += a.z; res.w += a.w;
        }
        if (add2) {
            float4 a = *(const float4*)(add2 + idx);
            res.x += a.x; res.y += a.y; res.z += a.z; res.w += a.w;
        }
        if (out) *(float4*)(out + idx) = res;
        if (out2) {
            if (out2_assign) {
                *(float4*)(out2 + idx) = res;
            } else {
                float4 o = *(const float4*)(out2 + idx);
                o.x += res.x; o.y += res.y; o.z += res.z; o.w += res.w;
                *(float4*)(out2 + idx) = o;
            }
        }
    }
}

// ---------------------------------------------------------------------------
extern "C" void kernel_launch(void* const* d_in, const int* in_sizes, int n_in,
                              void* d_out, int out_size, void* d_ws, size_t ws_size,
                              hipStream_t stream)
{
    const float* u        = (const float*)d_in[0];
    const float* it       = (const float*)d_in[1];
    const float* text     = (const float*)d_in[2];
    const float* W        = (const float*)d_in[3];
    const float* b        = (const float*)d_in[4];
    const float* adj_vals = (const float*)d_in[5];
    const float* t_vals   = (const float*)d_in[6];
    const int*   adj_rows = (const int*)d_in[7];
    const int*   adj_cols = (const int*)d_in[8];
    const int*   t_rows   = (const int*)d_in[9];
    const int*   t_cols   = (const int*)d_in[10];
    const int E = in_sizes[5];

    float* out = (float*)d_out;

    // per-bucket capacity: mean + 12.5% + 1024  (E=2.4M -> 11570, +~18 sigma)
    const int capbuck = E / NBUCKF + E / (NBUCKF * 8) + 1024;

    // ---- workspace carve ----
    char* p = (char*)d_ws;
    size_t used = 0;
    auto carve = [&](size_t bytes) {
        char* q = p + used;
        used += (bytes + 255) & ~(size_t)255;
        return q;
    };
    float* A      = (float*)carve((size_t)NNODE * LAT * 4);
    float* B      = (float*)carve((size_t)NNODE * LAT * 4);
    float* tf     = (float*)carve((size_t)ITEM * LAT * 4);
    int*   rpA    = (int*)  carve((size_t)RP * 4);
    int*   rpT    = (int*)  carve((size_t)RP * 4);
    u64*   epkA   = (u64*)  carve((size_t)E * 8);
    u64*   epkT   = (u64*)  carve((size_t)E * 8);
    int*   bcurA  = (int*)  carve((size_t)NBUCKF * 4);
    int*   bcurT  = (int*)  carve((size_t)NBUCKF * 4);
    u64*   blistA = (u64*)  carve((size_t)NBUCKF * capbuck * 8);
    u64*   blistT = (u64*)  carve((size_t)NBUCKF * capbuck * 8);
    (void)ws_size;   // ~177 MB; harness provided >= 242 MB in prior rounds

    const int sblk = (NNODE + 3) / 4;
    const int gblk = (ITEM + 63) / 64;
    const dim3 pgrid((E + CHUNK - 1) / CHUNK, 2);
    const dim3 cgrid(NBUCKF, 2);

    // ---- GEMM + normalize ----
    gemm_norm_kernel<<<gblk, 256, 0, stream>>>(text, W, b, tf, ITEM);

    // ---- build both CSRs (atomic-light two-pass) ----
    hipMemsetAsync(bcurA, 0, (size_t)2 * NBUCKF * 4, stream);  // bcurA|bcurT contig
    partition_kernel<<<pgrid, 256, 0, stream>>>(
        adj_rows, adj_cols, adj_vals, t_rows, t_cols, t_vals,
        blistA, blistT, bcurA, bcurT, capbuck, E);
    buildcsr_kernel<<<cgrid, 256, 0, stream>>>(
        blistA, blistT, bcurA, bcurT, rpA, rpT, epkA, epkT, capbuck);

    // ---- A = 0.2 * spmm(t, concat(u, i)) ----
    spmm_kernel<<<sblk, 256, 0, stream>>>(rpT, epkT, u, it, 0.2f,
                                          nullptr, nullptr, A, nullptr, 0, NNODE);
    // ---- B = e1 = spmm(adj, concat(u, tf)) ----
    spmm_kernel<<<sblk, 256, 0, stream>>>(rpA, epkA, u, tf, 1.0f,
                                          nullptr, nullptr, B, nullptr, 0, NNODE);
    // ---- A = embeds = e2 + A(lam*ta) + B(e1) ; out = embeds ----
    spmm_kernel<<<sblk, 256, 0, stream>>>(rpA, epkA, B, it, 1.0f,
                                          A, B, A, out, 1, NNODE);
    // ---- layer 1: B = spmm(adj, A) ; out += B ----
    spmm_kernel<<<sblk, 256, 0, stream>>>(rpA, epkA,
                                          A, A + (size_t)USER * LAT, 1.0f,
                                          nullptr, nullptr, B, out, 0, NNODE);
    // ---- layer 2: out += spmm(adj, B) ----
    spmm_kernel<<<sblk, 256, 0, stream>>>(rpA, epkA,
                                          B, B + (size_t)USER * LAT, 1.0f,
                                          nullptr, nullptr, nullptr, out, 0, NNODE);
}

// Round 8
// 854.290 us; speedup vs baseline: 1.4843x; 1.4843x over previous
//
#include <hip/hip_runtime.h>

#define USER  100000
#define ITEM  50000
#define NNODE 150000
#define LAT   64
#define TXT   768
#define RP    150016          // padded fil length (>= NNODE, 256B-mult)
#define NBUCK 8
#define BROWS (NNODE / NBUCK) // 18750 rows/bucket
#define SCHUNK 4096           // edges per block-chunk in scatter
#define CAP   64              // padded-CSR row capacity (max degree ~40)

typedef unsigned long long u64;

// ---------------------------------------------------------------------------
// Atomic-scatter SpMM (fallback path only)
// ---------------------------------------------------------------------------
__global__ __launch_bounds__(256) void spmm_atomic_kernel(
    const int* __restrict__ rows, const int* __restrict__ cols,
    const float* __restrict__ vals, float scale,
    const float* __restrict__ xu, const float* __restrict__ xi,
    float* __restrict__ out, int nedges)
{
    int e = blockIdx.x * 4 + (threadIdx.x >> 6);
    if (e >= nedges) return;
    int lane = threadIdx.x & 63;
    int r = rows[e];
    int c = cols[e];
    float v = vals[e] * scale;
    const float* x = (c < USER) ? (xu + (size_t)c * LAT)
                                : (xi + (size_t)(c - USER) * LAT);
    atomicAdd(&out[(size_t)r * LAT + lane], v * x[lane]);
}

// A = A + B ; out = A    (fallback path only)
__global__ __launch_bounds__(256) void combine_kernel(
    float* __restrict__ A, const float* __restrict__ B,
    float* __restrict__ out, int n4)
{
    int i = blockIdx.x * blockDim.x + threadIdx.x;
    if (i >= n4) return;
    float4 a = ((const float4*)A)[i];
    float4 b = ((const float4*)B)[i];
    a.x += b.x; a.y += b.y; a.z += b.z; a.w += b.w;
    ((float4*)A)[i]   = a;
    ((float4*)out)[i] = a;
}

// out += src    (fallback path only)
__global__ __launch_bounds__(256) void add_kernel(
    float* __restrict__ out, const float* __restrict__ src, int n4)
{
    int i = blockIdx.x * blockDim.x + threadIdx.x;
    if (i >= n4) return;
    float4 o = ((const float4*)out)[i];
    float4 s = ((const float4*)src)[i];
    o.x += s.x; o.y += s.y; o.z += s.z; o.w += s.w;
    ((float4*)out)[i] = o;
}

// ---------------------------------------------------------------------------
// LDS-tiled GEMM + row L2-normalize:  tf = l2norm(text @ W + b)
// ---------------------------------------------------------------------------
__global__ __launch_bounds__(256) void gemm_norm_kernel(
    const float* __restrict__ text, const float* __restrict__ W,
    const float* __restrict__ b, float* __restrict__ tf, int nitems)
{
    __shared__ float As[32][68];     // [k][row], pad 68 => conflict-free b128
    __shared__ float Bs[32][64];     // [k][col]

    const int tid = threadIdx.x;
    const int tx  = tid & 15;
    const int ty  = tid >> 4;
    const int row0 = blockIdx.x * 64;

    float acc[4][4] = {};

    const int lrow = tid >> 3;             // 0..31
    const int lk4  = (tid & 7) * 4;        // 0,4,...,28

    for (int k0 = 0; k0 < TXT; k0 += 32) {
#pragma unroll
        for (int half = 0; half < 2; ++half) {
            int r = lrow + half * 32;
            int gr = row0 + r;
            if (gr >= nitems) gr = nitems - 1;
            float4 tv = *(const float4*)(text + (size_t)gr * TXT + k0 + lk4);
            As[lk4 + 0][r] = tv.x;
            As[lk4 + 1][r] = tv.y;
            As[lk4 + 2][r] = tv.z;
            As[lk4 + 3][r] = tv.w;
        }
        const float4* wf = (const float4*)(W + (size_t)k0 * LAT);
        ((float4*)Bs)[tid]       = wf[tid];
        ((float4*)Bs)[tid + 256] = wf[tid + 256];
        __syncthreads();

#pragma unroll
        for (int k = 0; k < 32; ++k) {
            float4 a4 = *(const float4*)&As[k][ty * 4];
            float4 b4 = *(const float4*)&Bs[k][tx * 4];
            float av[4] = {a4.x, a4.y, a4.z, a4.w};
            float bv[4] = {b4.x, b4.y, b4.z, b4.w};
#pragma unroll
            for (int i = 0; i < 4; ++i)
#pragma unroll
                for (int j = 0; j < 4; ++j)
                    acc[i][j] = fmaf(av[i], bv[j], acc[i][j]);
        }
        __syncthreads();
    }

    float4 b4 = *(const float4*)(b + tx * 4);
    float bv[4] = {b4.x, b4.y, b4.z, b4.w};
#pragma unroll
    for (int i = 0; i < 4; ++i) {
        float v[4];
        float ss = 0.f;
#pragma unroll
        for (int j = 0; j < 4; ++j) {
            v[j] = acc[i][j] + bv[j];
            ss = fmaf(v[j], v[j], ss);
        }
        ss += __shfl_xor(ss, 1);
        ss += __shfl_xor(ss, 2);
        ss += __shfl_xor(ss, 4);
        ss += __shfl_xor(ss, 8);
        float inv = 1.0f / fmaxf(sqrtf(ss), 1e-12f);
        int gr = row0 + ty * 4 + i;
        if (gr < nitems) {
            float4 o = {v[0] * inv, v[1] * inv, v[2] * inv, v[3] * inv};
            *(float4*)(tf + (size_t)gr * LAT + tx * 4) = o;
        }
    }
}

// ---------------------------------------------------------------------------
// Padded-CSR scatter (round-6 proven): row r's records fill epk[r*64 ..].
// Bucketed (bucket = blockIdx.x&7 == XCD via round-robin dispatch) so each
// bucket's active dirty window stays in ONE XCD's L2. Atomics are spread
// over 150K fil addresses (NOT lockstep-contended).
// ---------------------------------------------------------------------------
__global__ __launch_bounds__(256) void scatter_pad_kernel(
    const int* __restrict__ rows, const int* __restrict__ cols,
    const float* __restrict__ vals, int* __restrict__ fil,
    u64* __restrict__ epk, int n)
{
    const int bucket = blockIdx.x & (NBUCK - 1);
    const int lo = bucket * BROWS;
    const int hi = lo + BROWS;
    const int base = (blockIdx.x >> 3) * SCHUNK;
    const int end = min(n, base + SCHUNK);
    for (int e = base + threadIdx.x; e < end; e += 256) {
        int r = rows[e];
        if (r >= lo && r < hi) {
            int pos = atomicAdd(&fil[r], 1);
            if (pos < CAP)   // mathematically never exceeded; memory-safety
                epk[((size_t)r << 6) + pos] =
                    ((u64)__float_as_uint(vals[e]) << 32) | (unsigned)cols[e];
        }
    }
}

// ---------------------------------------------------------------------------
// Padded-CSR gather SpMM, one row/wave, 4 edge-groups x 16 lanes x float4.
// Branch-free 8-deep pipeline: slots g,g+4,...,g+28 are always in-bounds
// (CAP=64); invalid slots clamp to c=0,v=0 (row 0 stays L1-hot, adds 0).
//   res[r] = scale * sum_e val*x[col] + add1[r] + add2[r]
//   if (out)  out[r]  = res
//   if (out2) out2[r] = res (assign) or out2[r] += res
// ---------------------------------------------------------------------------
__global__ __launch_bounds__(256) void spmm_kernel(
    const int* __restrict__ cnt, const u64* __restrict__ epk,
    const float* __restrict__ xu, const float* __restrict__ xi,
    float scale, const float* __restrict__ add1, const float* __restrict__ add2,
    float* __restrict__ out, float* __restrict__ out2, int out2_assign, int n)
{
    int r = blockIdx.x * 4 + (threadIdx.x >> 6);
    if (r >= n) return;
    int lane = threadIdx.x & 63;
    int g = lane >> 4;
    int l = lane & 15;

    const u64* rowp = epk + ((size_t)r << 6);
    const int deg = min(cnt[r], CAP);

    // phase 1: 8 independent record loads (always in-bounds)
    u64 pk[8];
#pragma unroll
    for (int i = 0; i < 8; ++i) pk[i] = rowp[g + i * 4];

    // phase 2: 8 independent gathers, clamped when slot >= deg
    float4 acc = {0.f, 0.f, 0.f, 0.f};
#pragma unroll
    for (int i = 0; i < 8; ++i) {
        int ee = g + i * 4;
        bool valid = ee < deg;
        int   c = valid ? (int)(unsigned)(pk[i] & 0xffffffffu) : 0;
        float v = valid ? __uint_as_float((unsigned)(pk[i] >> 32)) : 0.f;
        const float* x = (c < USER) ? (xu + (size_t)c * LAT)
                                    : (xi + (size_t)(c - USER) * LAT);
        float4 xv = *(const float4*)(x + 4 * l);
        acc.x = fmaf(v, xv.x, acc.x);
        acc.y = fmaf(v, xv.y, acc.y);
        acc.z = fmaf(v, xv.z, acc.z);
        acc.w = fmaf(v, xv.w, acc.w);
    }
    // extreme-degree safety (deg > 32): plain serial
    for (int ee = g + 32; ee < deg; ee += 4) {
        u64 p = rowp[ee];
        int c   = (int)(unsigned)(p & 0xffffffffu);
        float v = __uint_as_float((unsigned)(p >> 32));
        const float* x = (c < USER) ? (xu + (size_t)c * LAT)
                                    : (xi + (size_t)(c - USER) * LAT);
        float4 xv = *(const float4*)(x + 4 * l);
        acc.x = fmaf(v, xv.x, acc.x);
        acc.y = fmaf(v, xv.y, acc.y);
        acc.z = fmaf(v, xv.z, acc.z);
        acc.w = fmaf(v, xv.w, acc.w);
    }

#pragma unroll
    for (int off = 16; off <= 32; off <<= 1) {
        acc.x += __shfl_xor(acc.x, off);
        acc.y += __shfl_xor(acc.y, off);
        acc.z += __shfl_xor(acc.z, off);
        acc.w += __shfl_xor(acc.w, off);
    }
    if (g == 0) {
        size_t idx = (size_t)r * LAT + 4 * l;
        float4 res = {scale * acc.x, scale * acc.y, scale * acc.z, scale * acc.w};
        if (add1) {
            float4 a = *(const float4*)(add1 + idx);
            res.x += a.x; res.y += a.y; res.z += a.z; res.w += a.w;
        }
        if (add2) {
            float4 a = *(const float4*)(add2 + idx);
            res.x += a.x; res.y += a.y; res.z += a.z; res.w += a.w;
        }
        if (out) *(float4*)(out + idx) = res;
        if (out2) {
            if (out2_assign) {
                *(float4*)(out2 + idx) = res;
            } else {
                float4 o = *(const float4*)(out2 + idx);
                o.x += res.x; o.y += res.y; o.z += res.z; o.w += res.w;
                *(float4*)(out2 + idx) = o;
            }
        }
    }
}

// ---------------------------------------------------------------------------
extern "C" void kernel_launch(void* const* d_in, const int* in_sizes, int n_in,
                              void* d_out, int out_size, void* d_ws, size_t ws_size,
                              hipStream_t stream)
{
    const float* u        = (const float*)d_in[0];
    const float* it       = (const float*)d_in[1];
    const float* text     = (const float*)d_in[2];
    const float* W        = (const float*)d_in[3];
    const float* b        = (const float*)d_in[4];
    const float* adj_vals = (const float*)d_in[5];
    const float* t_vals   = (const float*)d_in[6];
    const int*   adj_rows = (const int*)d_in[7];
    const int*   adj_cols = (const int*)d_in[8];
    const int*   t_rows   = (const int*)d_in[9];
    const int*   t_cols   = (const int*)d_in[10];
    const int E = in_sizes[5];

    float* out = (float*)d_out;

    // ---- workspace carve ----
    char* p = (char*)d_ws;
    size_t used = 0;
    auto carve = [&](size_t bytes) {
        char* q = p + used;
        used += (bytes + 255) & ~(size_t)255;
        return q;
    };
    float* A    = (float*)carve((size_t)NNODE * LAT * 4);
    float* B    = (float*)carve((size_t)NNODE * LAT * 4);
    float* tf   = (float*)carve((size_t)ITEM * LAT * 4);
    int*   filA = (int*)  carve((size_t)RP * 4);
    int*   filT = (int*)  carve((size_t)RP * 4);
    u64*   epkA = (u64*)  carve((size_t)NNODE * CAP * 8);
    u64*   epkT = (u64*)  carve((size_t)NNODE * CAP * 8);
    bool padded = (used <= ws_size);   // true on this harness (round 6 proven)

    const int sblk  = (NNODE + 3) / 4;
    const int gblk  = (ITEM + 63) / 64;
    const int scblk = ((E + SCHUNK - 1) / SCHUNK) * NBUCK;
    const int n4    = NNODE * LAT / 4;
    const int cblk  = (n4 + 255) / 256;

    // ---- GEMM + normalize ----
    gemm_norm_kernel<<<gblk, 256, 0, stream>>>(text, W, b, tf, ITEM);

    if (padded) {
        // ---- build both padded CSRs (no hist/scan) ----
        hipMemsetAsync(filA, 0, (size_t)RP * 4 * 2, stream);   // filA|filT contig
        scatter_pad_kernel<<<scblk, 256, 0, stream>>>(
            adj_rows, adj_cols, adj_vals, filA, epkA, E);
        scatter_pad_kernel<<<scblk, 256, 0, stream>>>(
            t_rows, t_cols, t_vals, filT, epkT, E);

        // ---- A = 0.2 * spmm(t, concat(u, i)) ----
        spmm_kernel<<<sblk, 256, 0, stream>>>(filT, epkT, u, it, 0.2f,
                                              nullptr, nullptr, A, nullptr, 0, NNODE);
        // ---- B = e1 = spmm(adj, concat(u, tf)) ----
        spmm_kernel<<<sblk, 256, 0, stream>>>(filA, epkA, u, tf, 1.0f,
                                              nullptr, nullptr, B, nullptr, 0, NNODE);
        // ---- A = embeds = e2 + A(lam*ta) + B(e1) ; out = embeds ----
        spmm_kernel<<<sblk, 256, 0, stream>>>(filA, epkA, B, it, 1.0f,
                                              A, B, A, out, 1, NNODE);
        // ---- layer 1: B = spmm(adj, A) ; out += B ----
        spmm_kernel<<<sblk, 256, 0, stream>>>(filA, epkA,
                                              A, A + (size_t)USER * LAT, 1.0f,
                                              nullptr, nullptr, B, out, 0, NNODE);
        // ---- layer 2: out += spmm(adj, B) ----
        spmm_kernel<<<sblk, 256, 0, stream>>>(filA, epkA,
                                              B, B + (size_t)USER * LAT, 1.0f,
                                              nullptr, nullptr, nullptr, out, 0, NNODE);
        return;
    }

    // ---- minimal fallback (tiny ws): dense atomic scatter everywhere ----
    const size_t nbuf = (size_t)NNODE * LAT * 4;
    const int ablk = (E + 3) / 4;
    hipMemsetAsync(A, 0, nbuf, stream);
    hipMemsetAsync(B, 0, nbuf, stream);
    spmm_atomic_kernel<<<ablk, 256, 0, stream>>>(t_rows, t_cols, t_vals, 0.2f,
                                                 u, it, A, E);
    spmm_atomic_kernel<<<ablk, 256, 0, stream>>>(adj_rows, adj_cols, adj_vals, 1.0f,
                                                 u, tf, B, E);
    spmm_atomic_kernel<<<ablk, 256, 0, stream>>>(adj_rows, adj_cols, adj_vals, 1.0f,
                                                 B, it, A, E);
    combine_kernel<<<cblk, 256, 0, stream>>>(A, B, out, n4);
    hipMemsetAsync(B, 0, nbuf, stream);
    spmm_atomic_kernel<<<ablk, 256, 0, stream>>>(adj_rows, adj_cols, adj_vals, 1.0f,
                                                 A, A + (size_t)USER * LAT, B, E);
    add_kernel<<<cblk, 256, 0, stream>>>(out, B, n4);
    hipMemsetAsync(A, 0, nbuf, stream);
    spmm_atomic_kernel<<<ablk, 256, 0, stream>>>(adj_rows, adj_cols, adj_vals, 1.0f,
                                                 B, B + (size_t)USER * LAT, A, E);
    add_kernel<<<cblk, 256, 0, stream>>>(out, A, n4);
}

// Round 9
// 753.076 us; speedup vs baseline: 1.6838x; 1.1344x over previous
//
#include <hip/hip_runtime.h>

#define USER  100000
#define ITEM  50000
#define NNODE 150000
#define LAT   64
#define TXT   768
#define RP    150016          // padded fil length (>= NNODE, 256B-mult)
#define NBUCK 8
#define BROWS (NNODE / NBUCK) // 18750 rows/bucket
#define SCHUNK 4096           // edges per block-chunk in scatter
#define CAP   64              // padded-CSR row capacity (max degree ~40)
#define GEMMB 782             // gemm blocks (ceil(ITEM/64))
#define GEMMPAD 784           // padded to multiple of 8 (keeps scatter bucket->XCD)

typedef unsigned long long u64;

// ===========================================================================
// GEMM body (shared by standalone kernel and mega-kernel)
// ===========================================================================
__device__ __forceinline__ void gemm_body(
    float (*As)[68], float (*Bs)[64],
    const float* __restrict__ text, const float* __restrict__ W,
    const float* __restrict__ b, float* __restrict__ tf,
    int nitems, int blk)
{
    const int tid = threadIdx.x;
    const int tx  = tid & 15;
    const int ty  = tid >> 4;
    const int row0 = blk * 64;

    float acc[4][4] = {};

    const int lrow = tid >> 3;             // 0..31
    const int lk4  = (tid & 7) * 4;        // 0,4,...,28

    for (int k0 = 0; k0 < TXT; k0 += 32) {
#pragma unroll
        for (int half = 0; half < 2; ++half) {
            int r = lrow + half * 32;
            int gr = row0 + r;
            if (gr >= nitems) gr = nitems - 1;
            float4 tv = *(const float4*)(text + (size_t)gr * TXT + k0 + lk4);
            As[lk4 + 0][r] = tv.x;
            As[lk4 + 1][r] = tv.y;
            As[lk4 + 2][r] = tv.z;
            As[lk4 + 3][r] = tv.w;
        }
        const float4* wf = (const float4*)(W + (size_t)k0 * LAT);
        ((float4*)Bs)[tid]       = wf[tid];
        ((float4*)Bs)[tid + 256] = wf[tid + 256];
        __syncthreads();

#pragma unroll
        for (int k = 0; k < 32; ++k) {
            float4 a4 = *(const float4*)&As[k][ty * 4];
            float4 b4 = *(const float4*)&Bs[k][tx * 4];
            float av[4] = {a4.x, a4.y, a4.z, a4.w};
            float bv[4] = {b4.x, b4.y, b4.z, b4.w};
#pragma unroll
            for (int i = 0; i < 4; ++i)
#pragma unroll
                for (int j = 0; j < 4; ++j)
                    acc[i][j] = fmaf(av[i], bv[j], acc[i][j]);
        }
        __syncthreads();
    }

    float4 b4 = *(const float4*)(b + tx * 4);
    float bv[4] = {b4.x, b4.y, b4.z, b4.w};
#pragma unroll
    for (int i = 0; i < 4; ++i) {
        float v[4];
        float ss = 0.f;
#pragma unroll
        for (int j = 0; j < 4; ++j) {
            v[j] = acc[i][j] + bv[j];
            ss = fmaf(v[j], v[j], ss);
        }
        ss += __shfl_xor(ss, 1);
        ss += __shfl_xor(ss, 2);
        ss += __shfl_xor(ss, 4);
        ss += __shfl_xor(ss, 8);
        float inv = 1.0f / fmaxf(sqrtf(ss), 1e-12f);
        int gr = row0 + ty * 4 + i;
        if (gr < nitems) {
            float4 o = {v[0] * inv, v[1] * inv, v[2] * inv, v[3] * inv};
            *(float4*)(tf + (size_t)gr * LAT + tx * 4) = o;
        }
    }
}

// ===========================================================================
// Scatter body (padded CSR, bucketed: bucket == XCD via round-robin dispatch)
// ===========================================================================
__device__ __forceinline__ void scatter_body(
    const int* __restrict__ rows, const int* __restrict__ cols,
    const float* __restrict__ vals, int* __restrict__ fil,
    u64* __restrict__ epk, int n, int bucket, int chunk)
{
    const int lo = bucket * BROWS;
    const int hi = lo + BROWS;
    const int base = chunk * SCHUNK;
    const int end = min(n, base + SCHUNK);
    for (int e = base + threadIdx.x; e < end; e += 256) {
        int r = rows[e];
        if (r >= lo && r < hi) {
            int pos = atomicAdd(&fil[r], 1);
            if (pos < CAP)   // mathematically never exceeded; memory-safety
                epk[((size_t)r << 6) + pos] =
                    ((u64)__float_as_uint(vals[e]) << 32) | (unsigned)cols[e];
        }
    }
}

// ===========================================================================
// K1 mega-kernel: gemm (blocks 0..781) || scatterA || scatterT.
// Complementary resources: gemm = VALU/LDS-bound, scatter = atomic-bound.
// Scatter region starts at block 784 (mult of 8) so bucket = bid&7 == XCD.
// ===========================================================================
__global__ __launch_bounds__(256) void mega1_kernel(
    const float* __restrict__ text, const float* __restrict__ W,
    const float* __restrict__ b, float* __restrict__ tf, int nitems,
    const int* __restrict__ arows, const int* __restrict__ acols,
    const float* __restrict__ avals, int* __restrict__ filA, u64* __restrict__ epkA,
    const int* __restrict__ trows, const int* __restrict__ tcols,
    const float* __restrict__ tvals, int* __restrict__ filT, u64* __restrict__ epkT,
    int nedges, int nchunk)
{
    __shared__ float As[32][68];
    __shared__ float Bs[32][64];

    const int bid = blockIdx.x;
    if (bid < GEMMPAD) {
        if (bid < GEMMB)
            gemm_body(As, Bs, text, W, b, tf, nitems, bid);
        return;
    }
    const int bid2   = bid - GEMMPAD;
    const int bucket = bid2 & 7;
    const int cm     = bid2 >> 3;
    if (cm < nchunk)
        scatter_body(arows, acols, avals, filA, epkA, nedges, bucket, cm);
    else
        scatter_body(trows, tcols, tvals, filT, epkT, nedges, bucket, cm - nchunk);
}

// standalone (fallback path)
__global__ __launch_bounds__(256) void gemm_norm_kernel(
    const float* __restrict__ text, const float* __restrict__ W,
    const float* __restrict__ b, float* __restrict__ tf, int nitems)
{
    __shared__ float As[32][68];
    __shared__ float Bs[32][64];
    gemm_body(As, Bs, text, W, b, tf, nitems, blockIdx.x);
}

// ===========================================================================
// SpMM row body: padded CSR, 4 edge-groups x 16 lanes x float4, two-batch
// gather: slots 0..15 unconditional (clamped); slots 16..31 + tail only
// under the wave-uniform deg>16 branch (deg uniform across the wave).
// ===========================================================================
__device__ __forceinline__ void spmm_row(
    int r, int lane, const int* __restrict__ cnt, const u64* __restrict__ epk,
    const float* __restrict__ xu, const float* __restrict__ xi,
    float scale, const float* __restrict__ add1, const float* __restrict__ add2,
    float* __restrict__ out, float* __restrict__ out2, int out2_assign)
{
    const int g = lane >> 4;
    const int l = lane & 15;

    const u64* rowp = epk + ((size_t)r << 6);
    const int deg = min(cnt[r], CAP);

    float4 acc = {0.f, 0.f, 0.f, 0.f};

    // batch 1: slots 0..15 (always in-bounds of the CAP=64 row)
    u64 pk[4];
#pragma unroll
    for (int i = 0; i < 4; ++i) pk[i] = rowp[g + i * 4];
#pragma unroll
    for (int i = 0; i < 4; ++i) {
        int ee = g + i * 4;
        bool valid = ee < deg;
        int   c = valid ? (int)(unsigned)(pk[i] & 0xffffffffu) : 0;
        float v = valid ? __uint_as_float((unsigned)(pk[i] >> 32)) : 0.f;
        const float* x = (c < USER) ? (xu + (size_t)c * LAT)
                                    : (xi + (size_t)(c - USER) * LAT);
        float4 xv = *(const float4*)(x + 4 * l);
        acc.x = fmaf(v, xv.x, acc.x);
        acc.y = fmaf(v, xv.y, acc.y);
        acc.z = fmaf(v, xv.z, acc.z);
        acc.w = fmaf(v, xv.w, acc.w);
    }

    if (deg > 16) {                       // wave-uniform branch
        u64 pk2[4];
#pragma unroll
        for (int i = 0; i < 4; ++i) pk2[i] = rowp[16 + g + i * 4];
#pragma unroll
        for (int i = 0; i < 4; ++i) {
            int ee = 16 + g + i * 4;
            bool valid = ee < deg;
            int   c = valid ? (int)(unsigned)(pk2[i] & 0xffffffffu) : 0;
            float v = valid ? __uint_as_float((unsigned)(pk2[i] >> 32)) : 0.f;
            const float* x = (c < USER) ? (xu + (size_t)c * LAT)
                                        : (xi + (size_t)(c - USER) * LAT);
            float4 xv = *(const float4*)(x + 4 * l);
            acc.x = fmaf(v, xv.x, acc.x);
            acc.y = fmaf(v, xv.y, acc.y);
            acc.z = fmaf(v, xv.z, acc.z);
            acc.w = fmaf(v, xv.w, acc.w);
        }
        // extreme-degree safety (deg > 32)
        for (int ee = 32 + g; ee < deg; ee += 4) {
            u64 p = rowp[ee];
            int   c = (int)(unsigned)(p & 0xffffffffu);
            float v = __uint_as_float((unsigned)(p >> 32));
            const float* x = (c < USER) ? (xu + (size_t)c * LAT)
                                        : (xi + (size_t)(c - USER) * LAT);
            float4 xv = *(const float4*)(x + 4 * l);
            acc.x = fmaf(v, xv.x, acc.x);
            acc.y = fmaf(v, xv.y, acc.y);
            acc.z = fmaf(v, xv.z, acc.z);
            acc.w = fmaf(v, xv.w, acc.w);
        }
    }

#pragma unroll
    for (int off = 16; off <= 32; off <<= 1) {
        acc.x += __shfl_xor(acc.x, off);
        acc.y += __shfl_xor(acc.y, off);
        acc.z += __shfl_xor(acc.z, off);
        acc.w += __shfl_xor(acc.w, off);
    }
    if (g == 0) {
        size_t idx = (size_t)r * LAT + 4 * l;
        float4 res = {scale * acc.x, scale * acc.y, scale * acc.z, scale * acc.w};
        if (add1) {
            float4 a = *(const float4*)(add1 + idx);
            res.x += a.x; res.y += a.y; res.z += a.z; res.w += a.w;
        }
        if (add2) {
            float4 a = *(const float4*)(add2 + idx);
            res.x += a.x; res.y += a.y; res.z += a.z; res.w += a.w;
        }
        if (out) *(float4*)(out + idx) = res;
        if (out2) {
            if (out2_assign) {
                *(float4*)(out2 + idx) = res;
            } else {
                float4 o = *(const float4*)(out2 + idx);
                o.x += res.x; o.y += res.y; o.z += res.z; o.w += res.w;
                *(float4*)(out2 + idx) = o;
            }
        }
    }
}

__global__ __launch_bounds__(256) void spmm_kernel(
    const int* __restrict__ cnt, const u64* __restrict__ epk,
    const float* __restrict__ xu, const float* __restrict__ xi,
    float scale, const float* __restrict__ add1, const float* __restrict__ add2,
    float* __restrict__ out, float* __restrict__ out2, int out2_assign, int n)
{
    int r = blockIdx.x * 4 + (threadIdx.x >> 6);
    if (r >= n) return;
    spmm_row(r, threadIdx.x & 63, cnt, epk, xu, xi, scale,
             add1, add2, out, out2, out2_assign);
}

// K2: two independent SpMMs in one grid (parity split)
__global__ __launch_bounds__(256) void spmm_pair_kernel(
    const int* __restrict__ cnt0, const u64* __restrict__ epk0,
    const float* __restrict__ xu0, const float* __restrict__ xi0,
    float s0, float* __restrict__ out0,
    const int* __restrict__ cnt1, const u64* __restrict__ epk1,
    const float* __restrict__ xu1, const float* __restrict__ xi1,
    float s1, float* __restrict__ out1, int n)
{
    int m  = blockIdx.x & 1;
    int r  = (blockIdx.x >> 1) * 4 + (threadIdx.x >> 6);
    if (r >= n) return;
    int lane = threadIdx.x & 63;
    if (m == 0)
        spmm_row(r, lane, cnt0, epk0, xu0, xi0, s0, nullptr, nullptr,
                 out0, nullptr, 0);
    else
        spmm_row(r, lane, cnt1, epk1, xu1, xi1, s1, nullptr, nullptr,
                 out1, nullptr, 0);
}

// ---------------------------------------------------------------------------
// Fallback-only kernels
// ---------------------------------------------------------------------------
__global__ __launch_bounds__(256) void spmm_atomic_kernel(
    const int* __restrict__ rows, const int* __restrict__ cols,
    const float* __restrict__ vals, float scale,
    const float* __restrict__ xu, const float* __restrict__ xi,
    float* __restrict__ out, int nedges)
{
    int e = blockIdx.x * 4 + (threadIdx.x >> 6);
    if (e >= nedges) return;
    int lane = threadIdx.x & 63;
    int r = rows[e];
    int c = cols[e];
    float v = vals[e] * scale;
    const float* x = (c < USER) ? (xu + (size_t)c * LAT)
                                : (xi + (size_t)(c - USER) * LAT);
    atomicAdd(&out[(size_t)r * LAT + lane], v * x[lane]);
}

__global__ __launch_bounds__(256) void combine_kernel(
    float* __restrict__ A, const float* __restrict__ B,
    float* __restrict__ out, int n4)
{
    int i = blockIdx.x * blockDim.x + threadIdx.x;
    if (i >= n4) return;
    float4 a = ((const float4*)A)[i];
    float4 b = ((const float4*)B)[i];
    a.x += b.x; a.y += b.y; a.z += b.z; a.w += b.w;
    ((float4*)A)[i]   = a;
    ((float4*)out)[i] = a;
}

__global__ __launch_bounds__(256) void add_kernel(
    float* __restrict__ out, const float* __restrict__ src, int n4)
{
    int i = blockIdx.x * blockDim.x + threadIdx.x;
    if (i >= n4) return;
    float4 o = ((const float4*)out)[i];
    float4 s = ((const float4*)src)[i];
    o.x += s.x; o.y += s.y; o.z += s.z; o.w += s.w;
    ((float4*)out)[i] = o;
}

// ---------------------------------------------------------------------------
extern "C" void kernel_launch(void* const* d_in, const int* in_sizes, int n_in,
                              void* d_out, int out_size, void* d_ws, size_t ws_size,
                              hipStream_t stream)
{
    const float* u        = (const float*)d_in[0];
    const float* it       = (const float*)d_in[1];
    const float* text     = (const float*)d_in[2];
    const float* W        = (const float*)d_in[3];
    const float* b        = (const float*)d_in[4];
    const float* adj_vals = (const float*)d_in[5];
    const float* t_vals   = (const float*)d_in[6];
    const int*   adj_rows = (const int*)d_in[7];
    const int*   adj_cols = (const int*)d_in[8];
    const int*   t_rows   = (const int*)d_in[9];
    const int*   t_cols   = (const int*)d_in[10];
    const int E = in_sizes[5];

    float* out = (float*)d_out;

    // ---- workspace carve ----
    char* p = (char*)d_ws;
    size_t used = 0;
    auto carve = [&](size_t bytes) {
        char* q = p + used;
        used += (bytes + 255) & ~(size_t)255;
        return q;
    };
    float* A    = (float*)carve((size_t)NNODE * LAT * 4);
    float* B    = (float*)carve((size_t)NNODE * LAT * 4);
    float* tf   = (float*)carve((size_t)ITEM * LAT * 4);
    int*   filA = (int*)  carve((size_t)RP * 4);
    int*   filT = (int*)  carve((size_t)RP * 4);
    u64*   epkA = (u64*)  carve((size_t)NNODE * CAP * 8);
    u64*   epkT = (u64*)  carve((size_t)NNODE * CAP * 8);
    bool padded = (used <= ws_size);   // proven true on this harness (round 6+)

    const int sblk   = (NNODE + 3) / 4;
    const int nchunk = (E + SCHUNK - 1) / SCHUNK;
    const int n4     = NNODE * LAT / 4;
    const int cblk   = (n4 + 255) / 256;

    if (padded) {
        // ---- K1: gemm || scatterA || scatterT ----
        hipMemsetAsync(filA, 0, (size_t)RP * 4 * 2, stream);   // filA|filT contig
        mega1_kernel<<<GEMMPAD + 2 * nchunk * NBUCK, 256, 0, stream>>>(
            text, W, b, tf, ITEM,
            adj_rows, adj_cols, adj_vals, filA, epkA,
            t_rows, t_cols, t_vals, filT, epkT, E, nchunk);

        // ---- K2: A = 0.2*spmm(t, [u;i])  ||  B = e1 = spmm(adj, [u;tf]) ----
        spmm_pair_kernel<<<sblk * 2, 256, 0, stream>>>(
            filT, epkT, u, it, 0.2f, A,
            filA, epkA, u, tf, 1.0f, B, NNODE);

        // ---- K3: A = embeds = e2 + A(lam*ta) + B(e1) ; out = embeds ----
        spmm_kernel<<<sblk, 256, 0, stream>>>(filA, epkA, B, it, 1.0f,
                                              A, B, A, out, 1, NNODE);
        // ---- K4: layer 1: B = spmm(adj, A) ; out += B ----
        spmm_kernel<<<sblk, 256, 0, stream>>>(filA, epkA,
                                              A, A + (size_t)USER * LAT, 1.0f,
                                              nullptr, nullptr, B, out, 0, NNODE);
        // ---- K5: layer 2: out += spmm(adj, B) ----
        spmm_kernel<<<sblk, 256, 0, stream>>>(filA, epkA,
                                              B, B + (size_t)USER * LAT, 1.0f,
                                              nullptr, nullptr, nullptr, out, 0, NNODE);
        return;
    }

    // ---- minimal fallback (tiny ws): dense atomic scatter everywhere ----
    const size_t nbuf = (size_t)NNODE * LAT * 4;
    const int ablk = (E + 3) / 4;
    const int gblk = (ITEM + 63) / 64;
    gemm_norm_kernel<<<gblk, 256, 0, stream>>>(text, W, b, tf, ITEM);
    hipMemsetAsync(A, 0, nbuf, stream);
    hipMemsetAsync(B, 0, nbuf, stream);
    spmm_atomic_kernel<<<ablk, 256, 0, stream>>>(t_rows, t_cols, t_vals, 0.2f,
                                                 u, it, A, E);
    spmm_atomic_kernel<<<ablk, 256, 0, stream>>>(adj_rows, adj_cols, adj_vals, 1.0f,
                                                 u, tf, B, E);
    spmm_atomic_kernel<<<ablk, 256, 0, stream>>>(adj_rows, adj_cols, adj_vals, 1.0f,
                                                 B, it, A, E);
    combine_kernel<<<cblk, 256, 0, stream>>>(A, B, out, n4);
    hipMemsetAsync(B, 0, nbuf, stream);
    spmm_atomic_kernel<<<ablk, 256, 0, stream>>>(adj_rows, adj_cols, adj_vals, 1.0f,
                                                 A, A + (size_t)USER * LAT, B, E);
    add_kernel<<<cblk, 256, 0, stream>>>(out, B, n4);
    hipMemsetAsync(A, 0, nbuf, stream);
    spmm_atomic_kernel<<<ablk, 256, 0, stream>>>(adj_rows, adj_cols, adj_vals, 1.0f,
                                                 B, B + (size_t)USER * LAT, A, E);
    add_kernel<<<cblk, 256, 0, stream>>>(out, A, n4);
}

// Round 10
// 724.244 us; speedup vs baseline: 1.7509x; 1.0398x over previous
//
#include <hip/hip_runtime.h>

#define USER  100000
#define ITEM  50000
#define NNODE 150000
#define LAT   64
#define TXT   768
#define RP    150016          // padded fil length (>= NNODE, 256B-mult)
#define NBUCK 8
#define BROWS (NNODE / NBUCK) // 18750 rows/bucket
#define SCHUNK 4096           // edges per block-chunk in scatter
#define CAP   64              // padded-CSR row capacity (max degree ~40)
#define GEMMB 782             // gemm blocks (ceil(ITEM/64))
#define GEMMPAD 784           // padded to multiple of 8 (keeps scatter bucket->XCD)

typedef unsigned long long u64;

// ===========================================================================
// GEMM body (shared by standalone kernel and mega-kernel)
// ===========================================================================
__device__ __forceinline__ void gemm_body(
    float (*As)[68], float (*Bs)[64],
    const float* __restrict__ text, const float* __restrict__ W,
    const float* __restrict__ b, float* __restrict__ tf,
    int nitems, int blk)
{
    const int tid = threadIdx.x;
    const int tx  = tid & 15;
    const int ty  = tid >> 4;
    const int row0 = blk * 64;

    float acc[4][4] = {};

    const int lrow = tid >> 3;             // 0..31
    const int lk4  = (tid & 7) * 4;        // 0,4,...,28

    for (int k0 = 0; k0 < TXT; k0 += 32) {
#pragma unroll
        for (int half = 0; half < 2; ++half) {
            int r = lrow + half * 32;
            int gr = row0 + r;
            if (gr >= nitems) gr = nitems - 1;
            float4 tv = *(const float4*)(text + (size_t)gr * TXT + k0 + lk4);
            As[lk4 + 0][r] = tv.x;
            As[lk4 + 1][r] = tv.y;
            As[lk4 + 2][r] = tv.z;
            As[lk4 + 3][r] = tv.w;
        }
        const float4* wf = (const float4*)(W + (size_t)k0 * LAT);
        ((float4*)Bs)[tid]       = wf[tid];
        ((float4*)Bs)[tid + 256] = wf[tid + 256];
        __syncthreads();

#pragma unroll
        for (int k = 0; k < 32; ++k) {
            float4 a4 = *(const float4*)&As[k][ty * 4];
            float4 b4 = *(const float4*)&Bs[k][tx * 4];
            float av[4] = {a4.x, a4.y, a4.z, a4.w};
            float bv[4] = {b4.x, b4.y, b4.z, b4.w};
#pragma unroll
            for (int i = 0; i < 4; ++i)
#pragma unroll
                for (int j = 0; j < 4; ++j)
                    acc[i][j] = fmaf(av[i], bv[j], acc[i][j]);
        }
        __syncthreads();
    }

    float4 b4 = *(const float4*)(b + tx * 4);
    float bv[4] = {b4.x, b4.y, b4.z, b4.w};
#pragma unroll
    for (int i = 0; i < 4; ++i) {
        float v[4];
        float ss = 0.f;
#pragma unroll
        for (int j = 0; j < 4; ++j) {
            v[j] = acc[i][j] + bv[j];
            ss = fmaf(v[j], v[j], ss);
        }
        ss += __shfl_xor(ss, 1);
        ss += __shfl_xor(ss, 2);
        ss += __shfl_xor(ss, 4);
        ss += __shfl_xor(ss, 8);
        float inv = 1.0f / fmaxf(sqrtf(ss), 1e-12f);
        int gr = row0 + ty * 4 + i;
        if (gr < nitems) {
            float4 o = {v[0] * inv, v[1] * inv, v[2] * inv, v[3] * inv};
            *(float4*)(tf + (size_t)gr * LAT + tx * 4) = o;
        }
    }
}

// ===========================================================================
// Scatter body: padded CSR, bucketed (bucket == XCD), 16-deep atomic
// pipeline. Phases: load rows -> load cols/vals -> issue ALL atomics
// (independent, back-to-back) -> stores. Breaks the per-edge
// atomic->waitcnt->store serial chain (round-9 scatter was latency-bound:
// VALU 16%, HBM 12%, occ 77% -- nothing saturated).
// ===========================================================================
__device__ __forceinline__ void scatter_body(
    const int* __restrict__ rows, const int* __restrict__ cols,
    const float* __restrict__ vals, int* __restrict__ fil,
    u64* __restrict__ epk, int n, int bucket, int chunk)
{
    const int lo = bucket * BROWS;
    const int hi = lo + BROWS;
    const int base = chunk * SCHUNK + threadIdx.x;

    int  r[16];
    bool m[16];
    u64  pk[16];
    int  pos[16];

#pragma unroll
    for (int i = 0; i < 16; ++i) {
        int e = base + i * 256;
        bool inb = e < n;
        int rr = inb ? rows[e] : -1;
        r[i] = rr;
        m[i] = inb && (rr >= lo) && (rr < hi);
    }
#pragma unroll
    for (int i = 0; i < 16; ++i) {
        int e = base + i * 256;
        if (m[i])
            pk[i] = ((u64)__float_as_uint(vals[e]) << 32) | (unsigned)cols[e];
    }
#pragma unroll
    for (int i = 0; i < 16; ++i)
        if (m[i]) pos[i] = atomicAdd(&fil[r[i]], 1);
#pragma unroll
    for (int i = 0; i < 16; ++i)
        if (m[i] && pos[i] < CAP)   // mathematically never exceeded; safety
            epk[((size_t)r[i] << 6) + pos[i]] = pk[i];
}

// ===========================================================================
// K1 mega-kernel: gemm (blocks 0..781) || scatterA || scatterT.
// Scatter region starts at block 784 (mult of 8) so bucket = bid&7 == XCD.
// ===========================================================================
__global__ __launch_bounds__(256) void mega1_kernel(
    const float* __restrict__ text, const float* __restrict__ W,
    const float* __restrict__ b, float* __restrict__ tf, int nitems,
    const int* __restrict__ arows, const int* __restrict__ acols,
    const float* __restrict__ avals, int* __restrict__ filA, u64* __restrict__ epkA,
    const int* __restrict__ trows, const int* __restrict__ tcols,
    const float* __restrict__ tvals, int* __restrict__ filT, u64* __restrict__ epkT,
    int nedges, int nchunk)
{
    __shared__ float As[32][68];
    __shared__ float Bs[32][64];

    const int bid = blockIdx.x;
    if (bid < GEMMPAD) {
        if (bid < GEMMB)
            gemm_body(As, Bs, text, W, b, tf, nitems, bid);
        return;
    }
    const int bid2   = bid - GEMMPAD;
    const int bucket = bid2 & 7;
    const int cm     = bid2 >> 3;
    if (cm < nchunk)
        scatter_body(arows, acols, avals, filA, epkA, nedges, bucket, cm);
    else
        scatter_body(trows, tcols, tvals, filT, epkT, nedges, bucket, cm - nchunk);
}

// standalone (fallback path)
__global__ __launch_bounds__(256) void gemm_norm_kernel(
    const float* __restrict__ text, const float* __restrict__ W,
    const float* __restrict__ b, float* __restrict__ tf, int nitems)
{
    __shared__ float As[32][68];
    __shared__ float Bs[32][64];
    gemm_body(As, Bs, text, W, b, tf, nitems, blockIdx.x);
}

// ===========================================================================
// SpMM row body: padded CSR, 4 edge-groups x 16 lanes x float4.
// Gathers are exec-mask predicated (no clamped dummy loads); batch 2 under
// the wave-uniform deg>16 branch.
// ===========================================================================
__device__ __forceinline__ void spmm_row(
    int r, int lane, const int* __restrict__ cnt, const u64* __restrict__ epk,
    const float* __restrict__ xu, const float* __restrict__ xi,
    float scale, const float* __restrict__ add1, const float* __restrict__ add2,
    float* __restrict__ out, float* __restrict__ out2, int out2_assign)
{
    const int g = lane >> 4;
    const int l = lane & 15;

    const u64* rowp = epk + ((size_t)r << 6);
    const int deg = min(cnt[r], CAP);

    float4 acc = {0.f, 0.f, 0.f, 0.f};

    // batch 1: slots 0..15 (record loads always in-bounds of CAP=64 row)
    u64 pk[4];
#pragma unroll
    for (int i = 0; i < 4; ++i) pk[i] = rowp[g + i * 4];
#pragma unroll
    for (int i = 0; i < 4; ++i) {
        int ee = g + i * 4;
        if (ee < deg) {
            int   c = (int)(unsigned)(pk[i] & 0xffffffffu);
            float v = __uint_as_float((unsigned)(pk[i] >> 32));
            const float* x = (c < USER) ? (xu + (size_t)c * LAT)
                                        : (xi + (size_t)(c - USER) * LAT);
            float4 xv = *(const float4*)(x + 4 * l);
            acc.x = fmaf(v, xv.x, acc.x);
            acc.y = fmaf(v, xv.y, acc.y);
            acc.z = fmaf(v, xv.z, acc.z);
            acc.w = fmaf(v, xv.w, acc.w);
        }
    }

    if (deg > 16) {                       // wave-uniform branch
        u64 pk2[4];
#pragma unroll
        for (int i = 0; i < 4; ++i) pk2[i] = rowp[16 + g + i * 4];
#pragma unroll
        for (int i = 0; i < 4; ++i) {
            int ee = 16 + g + i * 4;
            if (ee < deg) {
                int   c = (int)(unsigned)(pk2[i] & 0xffffffffu);
                float v = __uint_as_float((unsigned)(pk2[i] >> 32));
                const float* x = (c < USER) ? (xu + (size_t)c * LAT)
                                            : (xi + (size_t)(c - USER) * LAT);
                float4 xv = *(const float4*)(x + 4 * l);
                acc.x = fmaf(v, xv.x, acc.x);
                acc.y = fmaf(v, xv.y, acc.y);
                acc.z = fmaf(v, xv.z, acc.z);
                acc.w = fmaf(v, xv.w, acc.w);
            }
        }
        // extreme-degree safety (deg > 32)
        for (int ee = 32 + g; ee < deg; ee += 4) {
            u64 p = rowp[ee];
            int   c = (int)(unsigned)(p & 0xffffffffu);
            float v = __uint_as_float((unsigned)(p >> 32));
            const float* x = (c < USER) ? (xu + (size_t)c * LAT)
                                        : (xi + (size_t)(c - USER) * LAT);
            float4 xv = *(const float4*)(x + 4 * l);
            acc.x = fmaf(v, xv.x, acc.x);
            acc.y = fmaf(v, xv.y, acc.y);
            acc.z = fmaf(v, xv.z, acc.z);
            acc.w = fmaf(v, xv.w, acc.w);
        }
    }

#pragma unroll
    for (int off = 16; off <= 32; off <<= 1) {
        acc.x += __shfl_xor(acc.x, off);
        acc.y += __shfl_xor(acc.y, off);
        acc.z += __shfl_xor(acc.z, off);
        acc.w += __shfl_xor(acc.w, off);
    }
    if (g == 0) {
        size_t idx = (size_t)r * LAT + 4 * l;
        float4 res = {scale * acc.x, scale * acc.y, scale * acc.z, scale * acc.w};
        if (add1) {
            float4 a = *(const float4*)(add1 + idx);
            res.x += a.x; res.y += a.y; res.z += a.z; res.w += a.w;
        }
        if (add2) {
            float4 a = *(const float4*)(add2 + idx);
            res.x += a.x; res.y += a.y; res.z += a.z; res.w += a.w;
        }
        if (out) *(float4*)(out + idx) = res;
        if (out2) {
            if (out2_assign) {
                *(float4*)(out2 + idx) = res;
            } else {
                float4 o = *(const float4*)(out2 + idx);
                o.x += res.x; o.y += res.y; o.z += res.z; o.w += res.w;
                *(float4*)(out2 + idx) = o;
            }
        }
    }
}

__global__ __launch_bounds__(256) void spmm_kernel(
    const int* __restrict__ cnt, const u64* __restrict__ epk,
    const float* __restrict__ xu, const float* __restrict__ xi,
    float scale, const float* __restrict__ add1, const float* __restrict__ add2,
    float* __restrict__ out, float* __restrict__ out2, int out2_assign, int n)
{
    int r = blockIdx.x * 4 + (threadIdx.x >> 6);
    if (r >= n) return;
    spmm_row(r, threadIdx.x & 63, cnt, epk, xu, xi, scale,
             add1, add2, out, out2, out2_assign);
}

// K2: two independent SpMMs in one grid (parity split)
__global__ __launch_bounds__(256) void spmm_pair_kernel(
    const int* __restrict__ cnt0, const u64* __restrict__ epk0,
    const float* __restrict__ xu0, const float* __restrict__ xi0,
    float s0, float* __restrict__ out0,
    const int* __restrict__ cnt1, const u64* __restrict__ epk1,
    const float* __restrict__ xu1, const float* __restrict__ xi1,
    float s1, float* __restrict__ out1, int n)
{
    int m  = blockIdx.x & 1;
    int r  = (blockIdx.x >> 1) * 4 + (threadIdx.x >> 6);
    if (r >= n) return;
    int lane = threadIdx.x & 63;
    if (m == 0)
        spmm_row(r, lane, cnt0, epk0, xu0, xi0, s0, nullptr, nullptr,
                 out0, nullptr, 0);
    else
        spmm_row(r, lane, cnt1, epk1, xu1, xi1, s1, nullptr, nullptr,
                 out1, nullptr, 0);
}

// ---------------------------------------------------------------------------
// Fallback-only kernels
// ---------------------------------------------------------------------------
__global__ __launch_bounds__(256) void spmm_atomic_kernel(
    const int* __restrict__ rows, const int* __restrict__ cols,
    const float* __restrict__ vals, float scale,
    const float* __restrict__ xu, const float* __restrict__ xi,
    float* __restrict__ out, int nedges)
{
    int e = blockIdx.x * 4 + (threadIdx.x >> 6);
    if (e >= nedges) return;
    int lane = threadIdx.x & 63;
    int r = rows[e];
    int c = cols[e];
    float v = vals[e] * scale;
    const float* x = (c < USER) ? (xu + (size_t)c * LAT)
                                : (xi + (size_t)(c - USER) * LAT);
    atomicAdd(&out[(size_t)r * LAT + lane], v * x[lane]);
}

__global__ __launch_bounds__(256) void combine_kernel(
    float* __restrict__ A, const float* __restrict__ B,
    float* __restrict__ out, int n4)
{
    int i = blockIdx.x * blockDim.x + threadIdx.x;
    if (i >= n4) return;
    float4 a = ((const float4*)A)[i];
    float4 b = ((const float4*)B)[i];
    a.x += b.x; a.y += b.y; a.z += b.z; a.w += b.w;
    ((float4*)A)[i]   = a;
    ((float4*)out)[i] = a;
}

__global__ __launch_bounds__(256) void add_kernel(
    float* __restrict__ out, const float* __restrict__ src, int n4)
{
    int i = blockIdx.x * blockDim.x + threadIdx.x;
    if (i >= n4) return;
    float4 o = ((const float4*)out)[i];
    float4 s = ((const float4*)src)[i];
    o.x += s.x; o.y += s.y; o.z += s.z; o.w += s.w;
    ((float4*)out)[i] = o;
}

// ---------------------------------------------------------------------------
extern "C" void kernel_launch(void* const* d_in, const int* in_sizes, int n_in,
                              void* d_out, int out_size, void* d_ws, size_t ws_size,
                              hipStream_t stream)
{
    const float* u        = (const float*)d_in[0];
    const float* it       = (const float*)d_in[1];
    const float* text     = (const float*)d_in[2];
    const float* W        = (const float*)d_in[3];
    const float* b        = (const float*)d_in[4];
    const float* adj_vals = (const float*)d_in[5];
    const float* t_vals   = (const float*)d_in[6];
    const int*   adj_rows = (const int*)d_in[7];
    const int*   adj_cols = (const int*)d_in[8];
    const int*   t_rows   = (const int*)d_in[9];
    const int*   t_cols   = (const int*)d_in[10];
    const int E = in_sizes[5];

    float* out = (float*)d_out;

    // ---- workspace carve ----
    char* p = (char*)d_ws;
    size_t used = 0;
    auto carve = [&](size_t bytes) {
        char* q = p + used;
        used += (bytes + 255) & ~(size_t)255;
        return q;
    };
    float* A    = (float*)carve((size_t)NNODE * LAT * 4);
    float* B    = (float*)carve((size_t)NNODE * LAT * 4);
    float* tf   = (float*)carve((size_t)ITEM * LAT * 4);
    int*   filA = (int*)  carve((size_t)RP * 4);
    int*   filT = (int*)  carve((size_t)RP * 4);
    u64*   epkA = (u64*)  carve((size_t)NNODE * CAP * 8);
    u64*   epkT = (u64*)  carve((size_t)NNODE * CAP * 8);
    bool padded = (used <= ws_size);   // proven true on this harness (round 6+)

    const int sblk   = (NNODE + 3) / 4;
    const int nchunk = (E + SCHUNK - 1) / SCHUNK;
    const int n4     = NNODE * LAT / 4;
    const int cblk   = (n4 + 255) / 256;

    if (padded) {
        // ---- K1: gemm || scatterA || scatterT ----
        hipMemsetAsync(filA, 0, (size_t)RP * 4 * 2, stream);   // filA|filT contig
        mega1_kernel<<<GEMMPAD + 2 * nchunk * NBUCK, 256, 0, stream>>>(
            text, W, b, tf, ITEM,
            adj_rows, adj_cols, adj_vals, filA, epkA,
            t_rows, t_cols, t_vals, filT, epkT, E, nchunk);

        // ---- K2: A = 0.2*spmm(t, [u;i])  ||  B = e1 = spmm(adj, [u;tf]) ----
        spmm_pair_kernel<<<sblk * 2, 256, 0, stream>>>(
            filT, epkT, u, it, 0.2f, A,
            filA, epkA, u, tf, 1.0f, B, NNODE);

        // ---- K3: A = embeds = e2 + A(lam*ta) + B(e1)   (no out write) ----
        spmm_kernel<<<sblk, 256, 0, stream>>>(filA, epkA, B, it, 1.0f,
                                              A, B, A, nullptr, 0, NNODE);
        // ---- K4: B = g1 = spmm(adj, embeds)            (no out write) ----
        spmm_kernel<<<sblk, 256, 0, stream>>>(filA, epkA,
                                              A, A + (size_t)USER * LAT, 1.0f,
                                              nullptr, nullptr, B, nullptr, 0, NNODE);
        // ---- K5: out = embeds + g1 + spmm(adj, g1) ----
        spmm_kernel<<<sblk, 256, 0, stream>>>(filA, epkA,
                                              B, B + (size_t)USER * LAT, 1.0f,
                                              A, B, out, nullptr, 0, NNODE);
        return;
    }

    // ---- minimal fallback (tiny ws): dense atomic scatter everywhere ----
    const size_t nbuf = (size_t)NNODE * LAT * 4;
    const int ablk = (E + 3) / 4;
    const int gblk = (ITEM + 63) / 64;
    gemm_norm_kernel<<<gblk, 256, 0, stream>>>(text, W, b, tf, ITEM);
    hipMemsetAsync(A, 0, nbuf, stream);
    hipMemsetAsync(B, 0, nbuf, stream);
    spmm_atomic_kernel<<<ablk, 256, 0, stream>>>(t_rows, t_cols, t_vals, 0.2f,
                                                 u, it, A, E);
    spmm_atomic_kernel<<<ablk, 256, 0, stream>>>(adj_rows, adj_cols, adj_vals, 1.0f,
                                                 u, tf, B, E);
    spmm_atomic_kernel<<<ablk, 256, 0, stream>>>(adj_rows, adj_cols, adj_vals, 1.0f,
                                                 B, it, A, E);
    combine_kernel<<<cblk, 256, 0, stream>>>(A, B, out, n4);
    hipMemsetAsync(B, 0, nbuf, stream);
    spmm_atomic_kernel<<<ablk, 256, 0, stream>>>(adj_rows, adj_cols, adj_vals, 1.0f,
                                                 A, A + (size_t)USER * LAT, B, E);
    add_kernel<<<cblk, 256, 0, stream>>>(out, B, n4);
    hipMemsetAsync(A, 0, nbuf, stream);
    spmm_atomic_kernel<<<ablk, 256, 0, stream>>>(adj_rows, adj_cols, adj_vals, 1.0f,
                                                 B, B + (size_t)USER * LAT, A, E);
    add_kernel<<<cblk, 256, 0, stream>>>(out, A, n4);
}

// Round 11
// 704.197 us; speedup vs baseline: 1.8007x; 1.0285x over previous
//
#include <hip/hip_runtime.h>

#define USER  100000
#define ITEM  50000
#define NNODE 150000
#define LAT   64
#define TXT   768
#define RP    150016          // padded fil length (>= NNODE, 256B-mult)
#define NBUCK 8
#define BROWS (NNODE / NBUCK) // 18750 rows/bucket
#define SCHUNK 4096           // edges per block-chunk in scatter
#define CAP   64              // padded-CSR row capacity (max degree ~40)
#define GEMMB 782             // gemm blocks (ceil(ITEM/64))

typedef unsigned long long u64;

// ===========================================================================
// GEMM body (shared by standalone kernel and mega-kernel)
// ===========================================================================
__device__ __forceinline__ void gemm_body(
    float (*As)[68], float (*Bs)[64],
    const float* __restrict__ text, const float* __restrict__ W,
    const float* __restrict__ b, float* __restrict__ tf,
    int nitems, int blk)
{
    const int tid = threadIdx.x;
    const int tx  = tid & 15;
    const int ty  = tid >> 4;
    const int row0 = blk * 64;

    float acc[4][4] = {};

    const int lrow = tid >> 3;             // 0..31
    const int lk4  = (tid & 7) * 4;        // 0,4,...,28

    for (int k0 = 0; k0 < TXT; k0 += 32) {
#pragma unroll
        for (int half = 0; half < 2; ++half) {
            int r = lrow + half * 32;
            int gr = row0 + r;
            if (gr >= nitems) gr = nitems - 1;
            float4 tv = *(const float4*)(text + (size_t)gr * TXT + k0 + lk4);
            As[lk4 + 0][r] = tv.x;
            As[lk4 + 1][r] = tv.y;
            As[lk4 + 2][r] = tv.z;
            As[lk4 + 3][r] = tv.w;
        }
        const float4* wf = (const float4*)(W + (size_t)k0 * LAT);
        ((float4*)Bs)[tid]       = wf[tid];
        ((float4*)Bs)[tid + 256] = wf[tid + 256];
        __syncthreads();

#pragma unroll
        for (int k = 0; k < 32; ++k) {
            float4 a4 = *(const float4*)&As[k][ty * 4];
            float4 b4 = *(const float4*)&Bs[k][tx * 4];
            float av[4] = {a4.x, a4.y, a4.z, a4.w};
            float bv[4] = {b4.x, b4.y, b4.z, b4.w};
#pragma unroll
            for (int i = 0; i < 4; ++i)
#pragma unroll
                for (int j = 0; j < 4; ++j)
                    acc[i][j] = fmaf(av[i], bv[j], acc[i][j]);
        }
        __syncthreads();
    }

    float4 b4 = *(const float4*)(b + tx * 4);
    float bv[4] = {b4.x, b4.y, b4.z, b4.w};
#pragma unroll
    for (int i = 0; i < 4; ++i) {
        float v[4];
        float ss = 0.f;
#pragma unroll
        for (int j = 0; j < 4; ++j) {
            v[j] = acc[i][j] + bv[j];
            ss = fmaf(v[j], v[j], ss);
        }
        ss += __shfl_xor(ss, 1);
        ss += __shfl_xor(ss, 2);
        ss += __shfl_xor(ss, 4);
        ss += __shfl_xor(ss, 8);
        float inv = 1.0f / fmaxf(sqrtf(ss), 1e-12f);
        int gr = row0 + ty * 4 + i;
        if (gr < nitems) {
            float4 o = {v[0] * inv, v[1] * inv, v[2] * inv, v[3] * inv};
            *(float4*)(tf + (size_t)gr * LAT + tx * 4) = o;
        }
    }
}

// ===========================================================================
// Scatter body: padded CSR, bucketed (bucket == XCD), 16-deep atomic
// pipeline: load rows -> load cols/vals -> issue ALL atomics -> stores.
// ===========================================================================
__device__ __forceinline__ void scatter_body(
    const int* __restrict__ rows, const int* __restrict__ cols,
    const float* __restrict__ vals, int* __restrict__ fil,
    u64* __restrict__ epk, int n, int bucket, int chunk)
{
    const int lo = bucket * BROWS;
    const int hi = lo + BROWS;
    const int base = chunk * SCHUNK + threadIdx.x;

    int  r[16];
    bool m[16];
    u64  pk[16];
    int  pos[16];

#pragma unroll
    for (int i = 0; i < 16; ++i) {
        int e = base + i * 256;
        bool inb = e < n;
        int rr = inb ? rows[e] : -1;
        r[i] = rr;
        m[i] = inb && (rr >= lo) && (rr < hi);
    }
#pragma unroll
    for (int i = 0; i < 16; ++i) {
        int e = base + i * 256;
        if (m[i])
            pk[i] = ((u64)__float_as_uint(vals[e]) << 32) | (unsigned)cols[e];
    }
#pragma unroll
    for (int i = 0; i < 16; ++i)
        if (m[i]) pos[i] = atomicAdd(&fil[r[i]], 1);
#pragma unroll
    for (int i = 0; i < 16; ++i)
        if (m[i] && pos[i] < CAP)   // mathematically never exceeded; safety
            epk[((size_t)r[i] << 6) + pos[i]] = pk[i];
}

// ===========================================================================
// K1 mega-kernel: scatterA || scatterT || gemm, INTERLEAVED so the atomic
// pipe saturates from t=0 and gemm's VALU work runs in the scatter waves'
// atomic-stall shadow. Per 72-block group: 64 scatter + 8 gemm slots.
// 72 % 8 == 0  =>  scatter ordinal&7 == blockIdx%8 == XCD (bucket affinity).
// ===========================================================================
__global__ __launch_bounds__(256) void mega1_kernel(
    const float* __restrict__ text, const float* __restrict__ W,
    const float* __restrict__ b, float* __restrict__ tf, int nitems,
    const int* __restrict__ arows, const int* __restrict__ acols,
    const float* __restrict__ avals, int* __restrict__ filA, u64* __restrict__ epkA,
    const int* __restrict__ trows, const int* __restrict__ tcols,
    const float* __restrict__ tvals, int* __restrict__ filT, u64* __restrict__ epkT,
    int nedges, int nchunk, int nscat)
{
    __shared__ float As[32][68];
    __shared__ float Bs[32][64];

    const int bid = blockIdx.x;
    const int gi  = bid / 72;
    const int pos = bid % 72;

    if (pos < 64) {
        const int so = gi * 64 + pos;          // so & 7 == bid & 7 == XCD
        if (so >= nscat) return;
        const int bucket = so & 7;
        const int cm     = so >> 3;
        if (cm < nchunk)
            scatter_body(arows, acols, avals, filA, epkA, nedges, bucket, cm);
        else
            scatter_body(trows, tcols, tvals, filT, epkT, nedges, bucket, cm - nchunk);
    } else {
        const int go = gi * 8 + (pos - 64);
        if (go < GEMMB)
            gemm_body(As, Bs, text, W, b, tf, nitems, go);
    }
}

// standalone (fallback path)
__global__ __launch_bounds__(256) void gemm_norm_kernel(
    const float* __restrict__ text, const float* __restrict__ W,
    const float* __restrict__ b, float* __restrict__ tf, int nitems)
{
    __shared__ float As[32][68];
    __shared__ float Bs[32][64];
    gemm_body(As, Bs, text, W, b, tf, nitems, blockIdx.x);
}

// ===========================================================================
// SpMM row body: padded CSR, 4 edge-groups x 16 lanes x float4.
// Gathers exec-mask predicated; batch 2 under wave-uniform deg>16 branch.
// ===========================================================================
__device__ __forceinline__ void spmm_row(
    int r, int lane, const int* __restrict__ cnt, const u64* __restrict__ epk,
    const float* __restrict__ xu, const float* __restrict__ xi,
    float scale, const float* __restrict__ add1, const float* __restrict__ add2,
    float* __restrict__ out, float* __restrict__ out2, int out2_assign)
{
    const int g = lane >> 4;
    const int l = lane & 15;

    const u64* rowp = epk + ((size_t)r << 6);
    const int deg = min(cnt[r], CAP);

    float4 acc = {0.f, 0.f, 0.f, 0.f};

    // batch 1: slots 0..15 (record loads always in-bounds of CAP=64 row)
    u64 pk[4];
#pragma unroll
    for (int i = 0; i < 4; ++i) pk[i] = rowp[g + i * 4];
#pragma unroll
    for (int i = 0; i < 4; ++i) {
        int ee = g + i * 4;
        if (ee < deg) {
            int   c = (int)(unsigned)(pk[i] & 0xffffffffu);
            float v = __uint_as_float((unsigned)(pk[i] >> 32));
            const float* x = (c < USER) ? (xu + (size_t)c * LAT)
                                        : (xi + (size_t)(c - USER) * LAT);
            float4 xv = *(const float4*)(x + 4 * l);
            acc.x = fmaf(v, xv.x, acc.x);
            acc.y = fmaf(v, xv.y, acc.y);
            acc.z = fmaf(v, xv.z, acc.z);
            acc.w = fmaf(v, xv.w, acc.w);
        }
    }

    if (deg > 16) {                       // wave-uniform branch
        u64 pk2[4];
#pragma unroll
        for (int i = 0; i < 4; ++i) pk2[i] = rowp[16 + g + i * 4];
#pragma unroll
        for (int i = 0; i < 4; ++i) {
            int ee = 16 + g + i * 4;
            if (ee < deg) {
                int   c = (int)(unsigned)(pk2[i] & 0xffffffffu);
                float v = __uint_as_float((unsigned)(pk2[i] >> 32));
                const float* x = (c < USER) ? (xu + (size_t)c * LAT)
                                            : (xi + (size_t)(c - USER) * LAT);
                float4 xv = *(const float4*)(x + 4 * l);
                acc.x = fmaf(v, xv.x, acc.x);
                acc.y = fmaf(v, xv.y, acc.y);
                acc.z = fmaf(v, xv.z, acc.z);
                acc.w = fmaf(v, xv.w, acc.w);
            }
        }
        // extreme-degree safety (deg > 32)
        for (int ee = 32 + g; ee < deg; ee += 4) {
            u64 p = rowp[ee];
            int   c = (int)(unsigned)(p & 0xffffffffu);
            float v = __uint_as_float((unsigned)(p >> 32));
            const float* x = (c < USER) ? (xu + (size_t)c * LAT)
                                        : (xi + (size_t)(c - USER) * LAT);
            float4 xv = *(const float4*)(x + 4 * l);
            acc.x = fmaf(v, xv.x, acc.x);
            acc.y = fmaf(v, xv.y, acc.y);
            acc.z = fmaf(v, xv.z, acc.z);
            acc.w = fmaf(v, xv.w, acc.w);
        }
    }

#pragma unroll
    for (int off = 16; off <= 32; off <<= 1) {
        acc.x += __shfl_xor(acc.x, off);
        acc.y += __shfl_xor(acc.y, off);
        acc.z += __shfl_xor(acc.z, off);
        acc.w += __shfl_xor(acc.w, off);
    }
    if (g == 0) {
        size_t idx = (size_t)r * LAT + 4 * l;
        float4 res = {scale * acc.x, scale * acc.y, scale * acc.z, scale * acc.w};
        if (add1) {
            float4 a = *(const float4*)(add1 + idx);
            res.x += a.x; res.y += a.y; res.z += a.z; res.w += a.w;
        }
        if (add2) {
            float4 a = *(const float4*)(add2 + idx);
            res.x += a.x; res.y += a.y; res.z += a.z; res.w += a.w;
        }
        if (out) *(float4*)(out + idx) = res;
        if (out2) {
            if (out2_assign) {
                *(float4*)(out2 + idx) = res;
            } else {
                float4 o = *(const float4*)(out2 + idx);
                o.x += res.x; o.y += res.y; o.z += res.z; o.w += res.w;
                *(float4*)(out2 + idx) = o;
            }
        }
    }
}

__global__ __launch_bounds__(256) void spmm_kernel(
    const int* __restrict__ cnt, const u64* __restrict__ epk,
    const float* __restrict__ xu, const float* __restrict__ xi,
    float scale, const float* __restrict__ add1, const float* __restrict__ add2,
    float* __restrict__ out, float* __restrict__ out2, int out2_assign, int n)
{
    int r = blockIdx.x * 4 + (threadIdx.x >> 6);
    if (r >= n) return;
    spmm_row(r, threadIdx.x & 63, cnt, epk, xu, xi, scale,
             add1, add2, out, out2, out2_assign);
}

// K2: two independent SpMMs in one grid (parity split)
__global__ __launch_bounds__(256) void spmm_pair_kernel(
    const int* __restrict__ cnt0, const u64* __restrict__ epk0,
    const float* __restrict__ xu0, const float* __restrict__ xi0,
    float s0, float* __restrict__ out0,
    const int* __restrict__ cnt1, const u64* __restrict__ epk1,
    const float* __restrict__ xu1, const float* __restrict__ xi1,
    float s1, float* __restrict__ out1, int n)
{
    int m  = blockIdx.x & 1;
    int r  = (blockIdx.x >> 1) * 4 + (threadIdx.x >> 6);
    if (r >= n) return;
    int lane = threadIdx.x & 63;
    if (m == 0)
        spmm_row(r, lane, cnt0, epk0, xu0, xi0, s0, nullptr, nullptr,
                 out0, nullptr, 0);
    else
        spmm_row(r, lane, cnt1, epk1, xu1, xi1, s1, nullptr, nullptr,
                 out1, nullptr, 0);
}

// ---------------------------------------------------------------------------
// Fallback-only kernels
// ---------------------------------------------------------------------------
__global__ __launch_bounds__(256) void spmm_atomic_kernel(
    const int* __restrict__ rows, const int* __restrict__ cols,
    const float* __restrict__ vals, float scale,
    const float* __restrict__ xu, const float* __restrict__ xi,
    float* __restrict__ out, int nedges)
{
    int e = blockIdx.x * 4 + (threadIdx.x >> 6);
    if (e >= nedges) return;
    int lane = threadIdx.x & 63;
    int r = rows[e];
    int c = cols[e];
    float v = vals[e] * scale;
    const float* x = (c < USER) ? (xu + (size_t)c * LAT)
                                : (xi + (size_t)(c - USER) * LAT);
    atomicAdd(&out[(size_t)r * LAT + lane], v * x[lane]);
}

__global__ __launch_bounds__(256) void combine_kernel(
    float* __restrict__ A, const float* __restrict__ B,
    float* __restrict__ out, int n4)
{
    int i = blockIdx.x * blockDim.x + threadIdx.x;
    if (i >= n4) return;
    float4 a = ((const float4*)A)[i];
    float4 b = ((const float4*)B)[i];
    a.x += b.x; a.y += b.y; a.z += b.z; a.w += b.w;
    ((float4*)A)[i]   = a;
    ((float4*)out)[i] = a;
}

__global__ __launch_bounds__(256) void add_kernel(
    float* __restrict__ out, const float* __restrict__ src, int n4)
{
    int i = blockIdx.x * blockDim.x + threadIdx.x;
    if (i >= n4) return;
    float4 o = ((const float4*)out)[i];
    float4 s = ((const float4*)src)[i];
    o.x += s.x; o.y += s.y; o.z += s.z; o.w += s.w;
    ((float4*)out)[i] = o;
}

// ---------------------------------------------------------------------------
extern "C" void kernel_launch(void* const* d_in, const int* in_sizes, int n_in,
                              void* d_out, int out_size, void* d_ws, size_t ws_size,
                              hipStream_t stream)
{
    const float* u        = (const float*)d_in[0];
    const float* it       = (const float*)d_in[1];
    const float* text     = (const float*)d_in[2];
    const float* W        = (const float*)d_in[3];
    const float* b        = (const float*)d_in[4];
    const float* adj_vals = (const float*)d_in[5];
    const float* t_vals   = (const float*)d_in[6];
    const int*   adj_rows = (const int*)d_in[7];
    const int*   adj_cols = (const int*)d_in[8];
    const int*   t_rows   = (const int*)d_in[9];
    const int*   t_cols   = (const int*)d_in[10];
    const int E = in_sizes[5];

    float* out = (float*)d_out;

    // ---- workspace carve ----
    char* p = (char*)d_ws;
    size_t used = 0;
    auto carve = [&](size_t bytes) {
        char* q = p + used;
        used += (bytes + 255) & ~(size_t)255;
        return q;
    };
    float* A    = (float*)carve((size_t)NNODE * LAT * 4);
    float* B    = (float*)carve((size_t)NNODE * LAT * 4);
    float* tf   = (float*)carve((size_t)ITEM * LAT * 4);
    int*   filA = (int*)  carve((size_t)RP * 4);
    int*   filT = (int*)  carve((size_t)RP * 4);
    u64*   epkA = (u64*)  carve((size_t)NNODE * CAP * 8);
    u64*   epkT = (u64*)  carve((size_t)NNODE * CAP * 8);
    bool padded = (used <= ws_size);   // proven true on this harness (round 6+)

    const int sblk   = (NNODE + 3) / 4;
    const int nchunk = (E + SCHUNK - 1) / SCHUNK;
    const int nscat  = 2 * nchunk * NBUCK;
    const int ngrp   = (nscat + 63) / 64;      // 72-block groups
    const int n4     = NNODE * LAT / 4;
    const int cblk   = (n4 + 255) / 256;

    if (padded) {
        // ---- K1: scatterA || scatterT || gemm (interleaved) ----
        hipMemsetAsync(filA, 0, (size_t)RP * 4 * 2, stream);   // filA|filT contig
        mega1_kernel<<<ngrp * 72, 256, 0, stream>>>(
            text, W, b, tf, ITEM,
            adj_rows, adj_cols, adj_vals, filA, epkA,
            t_rows, t_cols, t_vals, filT, epkT, E, nchunk, nscat);

        // ---- K2: A = 0.2*spmm(t, [u;i])  ||  B = e1 = spmm(adj, [u;tf]) ----
        spmm_pair_kernel<<<sblk * 2, 256, 0, stream>>>(
            filT, epkT, u, it, 0.2f, A,
            filA, epkA, u, tf, 1.0f, B, NNODE);

        // ---- K3: A = embeds = e2 + A(lam*ta) + B(e1) ----
        spmm_kernel<<<sblk, 256, 0, stream>>>(filA, epkA, B, it, 1.0f,
                                              A, B, A, nullptr, 0, NNODE);
        // ---- K4: B = g1 = spmm(adj, embeds) ----
        spmm_kernel<<<sblk, 256, 0, stream>>>(filA, epkA,
                                              A, A + (size_t)USER * LAT, 1.0f,
                                              nullptr, nullptr, B, nullptr, 0, NNODE);
        // ---- K5: out = embeds + g1 + spmm(adj, g1) ----
        spmm_kernel<<<sblk, 256, 0, stream>>>(filA, epkA,
                                              B, B + (size_t)USER * LAT, 1.0f,
                                              A, B, out, nullptr, 0, NNODE);
        return;
    }

    // ---- minimal fallback (tiny ws): dense atomic scatter everywhere ----
    const size_t nbuf = (size_t)NNODE * LAT * 4;
    const int ablk = (E + 3) / 4;
    const int gblk = (ITEM + 63) / 64;
    gemm_norm_kernel<<<gblk, 256, 0, stream>>>(text, W, b, tf, ITEM);
    hipMemsetAsync(A, 0, nbuf, stream);
    hipMemsetAsync(B, 0, nbuf, stream);
    spmm_atomic_kernel<<<ablk, 256, 0, stream>>>(t_rows, t_cols, t_vals, 0.2f,
                                                 u, it, A, E);
    spmm_atomic_kernel<<<ablk, 256, 0, stream>>>(adj_rows, adj_cols, adj_vals, 1.0f,
                                                 u, tf, B, E);
    spmm_atomic_kernel<<<ablk, 256, 0, stream>>>(adj_rows, adj_cols, adj_vals, 1.0f,
                                                 B, it, A, E);
    combine_kernel<<<cblk, 256, 0, stream>>>(A, B, out, n4);
    hipMemsetAsync(B, 0, nbuf, stream);
    spmm_atomic_kernel<<<ablk, 256, 0, stream>>>(adj_rows, adj_cols, adj_vals, 1.0f,
                                                 A, A + (size_t)USER * LAT, B, E);
    add_kernel<<<cblk, 256, 0, stream>>>(out, B, n4);
    hipMemsetAsync(A, 0, nbuf, stream);
    spmm_atomic_kernel<<<ablk, 256, 0, stream>>>(adj_rows, adj_cols, adj_vals, 1.0f,
                                                 B, B + (size_t)USER * LAT, A, E);
    add_kernel<<<cblk, 256, 0, stream>>>(out, A, n4);
}

// Round 12
// 647.868 us; speedup vs baseline: 1.9573x; 1.0869x over previous
//
#include <hip/hip_runtime.h>
#include <hip/hip_fp16.h>

#define USER  100000
#define ITEM  50000
#define NNODE 150000
#define LAT   64
#define TXT   768
#define RP    150016          // padded fil length (>= NNODE, 256B-mult elems)
#define NBUCK 8
#define BROWS (NNODE / NBUCK) // 18750 rows/bucket
#define SCHUNK 4096           // edges per block-chunk in scatter
#define CAP   64              // padded-CSR row capacity (max degree ~40)
#define GEMMB 782             // gemm blocks (ceil(ITEM/64))

typedef unsigned long long u64;

// ---------------------------------------------------------------------------
// type helpers: fp32/fp16 stores and gathers
// ---------------------------------------------------------------------------
__device__ __forceinline__ void store4(float* p, float4 v) { *(float4*)p = v; }
__device__ __forceinline__ void store4(__half* p, float4 v)
{
    __half2* d = (__half2*)p;
    d[0] = __floats2half2_rn(v.x, v.y);
    d[1] = __floats2half2_rn(v.z, v.w);
}
__device__ __forceinline__ float4 load_x4(const float* x, int l)
{
    return *(const float4*)(x + 4 * l);
}
__device__ __forceinline__ float4 load_x4(const __half* x, int l)
{
    float2 raw = *(const float2*)(x + 4 * l);          // one 8B load
    __half2 h0 = *reinterpret_cast<const __half2*>(&raw.x);
    __half2 h1 = *reinterpret_cast<const __half2*>(&raw.y);
    float2 f0 = __half22float2(h0);
    float2 f1 = __half22float2(h1);
    return make_float4(f0.x, f0.y, f1.x, f1.y);
}

// ===========================================================================
// GEMM body (tf output type templated: fp16 in fast path)
// ===========================================================================
template<typename TFT>
__device__ __forceinline__ void gemm_body(
    float (*As)[68], float (*Bs)[64],
    const float* __restrict__ text, const float* __restrict__ W,
    const float* __restrict__ b, TFT* __restrict__ tf,
    int nitems, int blk)
{
    const int tid = threadIdx.x;
    const int tx  = tid & 15;
    const int ty  = tid >> 4;
    const int row0 = blk * 64;

    float acc[4][4] = {};

    const int lrow = tid >> 3;             // 0..31
    const int lk4  = (tid & 7) * 4;        // 0,4,...,28

    for (int k0 = 0; k0 < TXT; k0 += 32) {
#pragma unroll
        for (int half = 0; half < 2; ++half) {
            int r = lrow + half * 32;
            int gr = row0 + r;
            if (gr >= nitems) gr = nitems - 1;
            float4 tv = *(const float4*)(text + (size_t)gr * TXT + k0 + lk4);
            As[lk4 + 0][r] = tv.x;
            As[lk4 + 1][r] = tv.y;
            As[lk4 + 2][r] = tv.z;
            As[lk4 + 3][r] = tv.w;
        }
        const float4* wf = (const float4*)(W + (size_t)k0 * LAT);
        ((float4*)Bs)[tid]       = wf[tid];
        ((float4*)Bs)[tid + 256] = wf[tid + 256];
        __syncthreads();

#pragma unroll
        for (int k = 0; k < 32; ++k) {
            float4 a4 = *(const float4*)&As[k][ty * 4];
            float4 b4 = *(const float4*)&Bs[k][tx * 4];
            float av[4] = {a4.x, a4.y, a4.z, a4.w};
            float bv[4] = {b4.x, b4.y, b4.z, b4.w};
#pragma unroll
            for (int i = 0; i < 4; ++i)
#pragma unroll
                for (int j = 0; j < 4; ++j)
                    acc[i][j] = fmaf(av[i], bv[j], acc[i][j]);
        }
        __syncthreads();
    }

    float4 b4 = *(const float4*)(b + tx * 4);
    float bv[4] = {b4.x, b4.y, b4.z, b4.w};
#pragma unroll
    for (int i = 0; i < 4; ++i) {
        float v[4];
        float ss = 0.f;
#pragma unroll
        for (int j = 0; j < 4; ++j) {
            v[j] = acc[i][j] + bv[j];
            ss = fmaf(v[j], v[j], ss);
        }
        ss += __shfl_xor(ss, 1);
        ss += __shfl_xor(ss, 2);
        ss += __shfl_xor(ss, 4);
        ss += __shfl_xor(ss, 8);
        float inv = 1.0f / fmaxf(sqrtf(ss), 1e-12f);
        int gr = row0 + ty * 4 + i;
        if (gr < nitems)
            store4(tf + (size_t)gr * LAT + tx * 4,
                   make_float4(v[0] * inv, v[1] * inv, v[2] * inv, v[3] * inv));
    }
}

// ===========================================================================
// Scatter body: padded CSR, bucketed (bucket == XCD), 16-deep atomic pipeline
// ===========================================================================
__device__ __forceinline__ void scatter_body(
    const int* __restrict__ rows, const int* __restrict__ cols,
    const float* __restrict__ vals, int* __restrict__ fil,
    u64* __restrict__ epk, int n, int bucket, int chunk)
{
    const int lo = bucket * BROWS;
    const int hi = lo + BROWS;
    const int base = chunk * SCHUNK + threadIdx.x;

    int  r[16];
    bool m[16];
    u64  pk[16];
    int  pos[16];

#pragma unroll
    for (int i = 0; i < 16; ++i) {
        int e = base + i * 256;
        bool inb = e < n;
        int rr = inb ? rows[e] : -1;
        r[i] = rr;
        m[i] = inb && (rr >= lo) && (rr < hi);
    }
#pragma unroll
    for (int i = 0; i < 16; ++i) {
        int e = base + i * 256;
        if (m[i])
            pk[i] = ((u64)__float_as_uint(vals[e]) << 32) | (unsigned)cols[e];
    }
#pragma unroll
    for (int i = 0; i < 16; ++i)
        if (m[i]) pos[i] = atomicAdd(&fil[r[i]], 1);
#pragma unroll
    for (int i = 0; i < 16; ++i)
        if (m[i] && pos[i] < CAP)   // mathematically never exceeded; safety
            epk[((size_t)r[i] << 6) + pos[i]] = pk[i];
}

// ===========================================================================
// cvt body: fp32 -> fp16 copy of concat(u, it), grid-strided over slots.
// Pure BW work riding in mega1's dense slots (hidden in the atomic shadow).
// ===========================================================================
__device__ __forceinline__ void cvt_body(
    const float* __restrict__ u, const float* __restrict__ it,
    __half* __restrict__ u16, __half* __restrict__ it16,
    int slot, int nslots)
{
    const long NG  = (long)NNODE * LAT / 8;       // 8-elem groups
    const long UG  = (long)USER * LAT / 8;        // groups in u (divisible)
    const long stride = (long)nslots * 256;
    for (long g = (long)slot * 256 + threadIdx.x; g < NG; g += stride) {
        const float* s; __half* d; long off;
        if (g < UG) { s = u;  d = u16;  off = g * 8; }
        else        { s = it; d = it16; off = (g - UG) * 8; }
        const float4* s4 = (const float4*)(s + off);
        float4 a = s4[0], c = s4[1];
        __half2* d2 = (__half2*)(d + off);
        d2[0] = __floats2half2_rn(a.x, a.y);
        d2[1] = __floats2half2_rn(a.z, a.w);
        d2[2] = __floats2half2_rn(c.x, c.y);
        d2[3] = __floats2half2_rn(c.z, c.w);
    }
}

// ===========================================================================
// K1 mega-kernel: scatterA || scatterT || gemm || cvt, interleaved.
// Per 72-block group: 64 scatter + 8 dense slots (gemm first, then cvt).
// 72 % 8 == 0  =>  scatter ordinal&7 == blockIdx%8 == XCD (bucket affinity).
// ===========================================================================
template<typename TFT>
__global__ __launch_bounds__(256) void mega1_kernel(
    const float* __restrict__ text, const float* __restrict__ W,
    const float* __restrict__ b, TFT* __restrict__ tf, int nitems,
    const int* __restrict__ arows, const int* __restrict__ acols,
    const float* __restrict__ avals, int* __restrict__ filA, u64* __restrict__ epkA,
    const int* __restrict__ trows, const int* __restrict__ tcols,
    const float* __restrict__ tvals, int* __restrict__ filT, u64* __restrict__ epkT,
    int nedges, int nchunk, int nscat,
    const float* __restrict__ u, const float* __restrict__ it,
    __half* __restrict__ u16, __half* __restrict__ it16, int ncvt)
{
    __shared__ float As[32][68];
    __shared__ float Bs[32][64];

    const int bid = blockIdx.x;
    const int gi  = bid / 72;
    const int pos = bid % 72;

    if (pos < 64) {
        const int so = gi * 64 + pos;          // so & 7 == bid & 7 == XCD
        if (so >= nscat) return;
        const int bucket = so & 7;
        const int cm     = so >> 3;
        if (cm < nchunk)
            scatter_body(arows, acols, avals, filA, epkA, nedges, bucket, cm);
        else
            scatter_body(trows, tcols, tvals, filT, epkT, nedges, bucket, cm - nchunk);
    } else {
        const int go = gi * 8 + (pos - 64);
        if (go < GEMMB)
            gemm_body<TFT>(As, Bs, text, W, b, tf, nitems, go);
        else if (u16 && go - GEMMB < ncvt)
            cvt_body(u, it, u16, it16, go - GEMMB, ncvt);
    }
}

// standalone gemm (fallback path, fp32 tf)
__global__ __launch_bounds__(256) void gemm_norm_kernel(
    const float* __restrict__ text, const float* __restrict__ W,
    const float* __restrict__ b, float* __restrict__ tf, int nitems)
{
    __shared__ float As[32][68];
    __shared__ float Bs[32][64];
    gemm_body<float>(As, Bs, text, W, b, tf, nitems, blockIdx.x);
}

// ===========================================================================
// SpMM row body: padded CSR, 4 edge-groups x 16 lanes x float4 accum.
// Gather operand type XT (fp16 fast path: one 128B line per edge).
//   res[r] = scale * sum_e val*x[col] + add1[r] + add2[r]
//   out32[r] = res ; optionally out16[r] = res (fp16 copy for next gather)
// ===========================================================================
template<typename XT>
__device__ __forceinline__ void spmm_row(
    int r, int lane, const int* __restrict__ cnt, const u64* __restrict__ epk,
    const XT* __restrict__ xu, const XT* __restrict__ xi,
    float scale, const float* __restrict__ add1, const float* __restrict__ add2,
    float* __restrict__ out32, __half* __restrict__ out16)
{
    const int g = lane >> 4;
    const int l = lane & 15;

    const u64* rowp = epk + ((size_t)r << 6);
    const int deg = min(cnt[r], CAP);

    float4 acc = {0.f, 0.f, 0.f, 0.f};

    // batch 1: slots 0..15 (record loads always in-bounds of CAP=64 row)
    u64 pk[4];
#pragma unroll
    for (int i = 0; i < 4; ++i) pk[i] = rowp[g + i * 4];
#pragma unroll
    for (int i = 0; i < 4; ++i) {
        int ee = g + i * 4;
        if (ee < deg) {
            int   c = (int)(unsigned)(pk[i] & 0xffffffffu);
            float v = __uint_as_float((unsigned)(pk[i] >> 32));
            const XT* x = (c < USER) ? (xu + (size_t)c * LAT)
                                     : (xi + (size_t)(c - USER) * LAT);
            float4 xv = load_x4(x, l);
            acc.x = fmaf(v, xv.x, acc.x);
            acc.y = fmaf(v, xv.y, acc.y);
            acc.z = fmaf(v, xv.z, acc.z);
            acc.w = fmaf(v, xv.w, acc.w);
        }
    }

    if (deg > 16) {                       // wave-uniform branch
        u64 pk2[4];
#pragma unroll
        for (int i = 0; i < 4; ++i) pk2[i] = rowp[16 + g + i * 4];
#pragma unroll
        for (int i = 0; i < 4; ++i) {
            int ee = 16 + g + i * 4;
            if (ee < deg) {
                int   c = (int)(unsigned)(pk2[i] & 0xffffffffu);
                float v = __uint_as_float((unsigned)(pk2[i] >> 32));
                const XT* x = (c < USER) ? (xu + (size_t)c * LAT)
                                         : (xi + (size_t)(c - USER) * LAT);
                float4 xv = load_x4(x, l);
                acc.x = fmaf(v, xv.x, acc.x);
                acc.y = fmaf(v, xv.y, acc.y);
                acc.z = fmaf(v, xv.z, acc.z);
                acc.w = fmaf(v, xv.w, acc.w);
            }
        }
        // extreme-degree safety (deg > 32)
        for (int ee = 32 + g; ee < deg; ee += 4) {
            u64 p = rowp[ee];
            int   c = (int)(unsigned)(p & 0xffffffffu);
            float v = __uint_as_float((unsigned)(p >> 32));
            const XT* x = (c < USER) ? (xu + (size_t)c * LAT)
                                     : (xi + (size_t)(c - USER) * LAT);
            float4 xv = load_x4(x, l);
            acc.x = fmaf(v, xv.x, acc.x);
            acc.y = fmaf(v, xv.y, acc.y);
            acc.z = fmaf(v, xv.z, acc.z);
            acc.w = fmaf(v, xv.w, acc.w);
        }
    }

#pragma unroll
    for (int off = 16; off <= 32; off <<= 1) {
        acc.x += __shfl_xor(acc.x, off);
        acc.y += __shfl_xor(acc.y, off);
        acc.z += __shfl_xor(acc.z, off);
        acc.w += __shfl_xor(acc.w, off);
    }
    if (g == 0) {
        size_t idx = (size_t)r * LAT + 4 * l;
        float4 res = {scale * acc.x, scale * acc.y, scale * acc.z, scale * acc.w};
        if (add1) {
            float4 a = *(const float4*)(add1 + idx);
            res.x += a.x; res.y += a.y; res.z += a.z; res.w += a.w;
        }
        if (add2) {
            float4 a = *(const float4*)(add2 + idx);
            res.x += a.x; res.y += a.y; res.z += a.z; res.w += a.w;
        }
        *(float4*)(out32 + idx) = res;
        if (out16) store4(out16 + idx, res);
    }
}

template<typename XT>
__global__ __launch_bounds__(256) void spmm_kernel(
    const int* __restrict__ cnt, const u64* __restrict__ epk,
    const XT* __restrict__ xu, const XT* __restrict__ xi,
    float scale, const float* __restrict__ add1, const float* __restrict__ add2,
    float* __restrict__ out32, __half* __restrict__ out16, int n)
{
    int r = blockIdx.x * 4 + (threadIdx.x >> 6);
    if (r >= n) return;
    spmm_row<XT>(r, threadIdx.x & 63, cnt, epk, xu, xi, scale,
                 add1, add2, out32, out16);
}

// K2: two independent SpMMs in one grid (parity split)
template<typename XT>
__global__ __launch_bounds__(256) void spmm_pair_kernel(
    const int* __restrict__ cnt0, const u64* __restrict__ epk0,
    const XT* __restrict__ xu0, const XT* __restrict__ xi0,
    float s0, float* __restrict__ out0, __half* __restrict__ o16_0,
    const int* __restrict__ cnt1, const u64* __restrict__ epk1,
    const XT* __restrict__ xu1, const XT* __restrict__ xi1,
    float s1, float* __restrict__ out1, __half* __restrict__ o16_1, int n)
{
    int m  = blockIdx.x & 1;
    int r  = (blockIdx.x >> 1) * 4 + (threadIdx.x >> 6);
    if (r >= n) return;
    int lane = threadIdx.x & 63;
    if (m == 0)
        spmm_row<XT>(r, lane, cnt0, epk0, xu0, xi0, s0, nullptr, nullptr,
                     out0, o16_0);
    else
        spmm_row<XT>(r, lane, cnt1, epk1, xu1, xi1, s1, nullptr, nullptr,
                     out1, o16_1);
}

// ---------------------------------------------------------------------------
// Tiny-ws fallback kernels
// ---------------------------------------------------------------------------
__global__ __launch_bounds__(256) void spmm_atomic_kernel(
    const int* __restrict__ rows, const int* __restrict__ cols,
    const float* __restrict__ vals, float scale,
    const float* __restrict__ xu, const float* __restrict__ xi,
    float* __restrict__ out, int nedges)
{
    int e = blockIdx.x * 4 + (threadIdx.x >> 6);
    if (e >= nedges) return;
    int lane = threadIdx.x & 63;
    int r = rows[e];
    int c = cols[e];
    float v = vals[e] * scale;
    const float* x = (c < USER) ? (xu + (size_t)c * LAT)
                                : (xi + (size_t)(c - USER) * LAT);
    atomicAdd(&out[(size_t)r * LAT + lane], v * x[lane]);
}

__global__ __launch_bounds__(256) void combine_kernel(
    float* __restrict__ A, const float* __restrict__ B,
    float* __restrict__ out, int n4)
{
    int i = blockIdx.x * blockDim.x + threadIdx.x;
    if (i >= n4) return;
    float4 a = ((const float4*)A)[i];
    float4 b = ((const float4*)B)[i];
    a.x += b.x; a.y += b.y; a.z += b.z; a.w += b.w;
    ((float4*)A)[i]   = a;
    ((float4*)out)[i] = a;
}

__global__ __launch_bounds__(256) void add_kernel(
    float* __restrict__ out, const float* __restrict__ src, int n4)
{
    int i = blockIdx.x * blockDim.x + threadIdx.x;
    if (i >= n4) return;
    float4 o = ((const float4*)out)[i];
    float4 s = ((const float4*)src)[i];
    o.x += s.x; o.y += s.y; o.z += s.z; o.w += s.w;
    ((float4*)out)[i] = o;
}

// ---------------------------------------------------------------------------
extern "C" void kernel_launch(void* const* d_in, const int* in_sizes, int n_in,
                              void* d_out, int out_size, void* d_ws, size_t ws_size,
                              hipStream_t stream)
{
    const float* u        = (const float*)d_in[0];
    const float* it       = (const float*)d_in[1];
    const float* text     = (const float*)d_in[2];
    const float* W        = (const float*)d_in[3];
    const float* b        = (const float*)d_in[4];
    const float* adj_vals = (const float*)d_in[5];
    const float* t_vals   = (const float*)d_in[6];
    const int*   adj_rows = (const int*)d_in[7];
    const int*   adj_cols = (const int*)d_in[8];
    const int*   t_rows   = (const int*)d_in[9];
    const int*   t_cols   = (const int*)d_in[10];
    const int E = in_sizes[5];

    float* out = (float*)d_out;

    const int sblk   = (NNODE + 3) / 4;
    const int nchunk = (E + SCHUNK - 1) / SCHUNK;
    const int nscat  = 2 * nchunk * NBUCK;
    const int ngrp   = (nscat + 63) / 64;      // 72-block groups
    const int ncvt   = ngrp * 8 - GEMMB;       // dense slots left for cvt
    const int n4     = NNODE * LAT / 4;
    const int cblk   = (n4 + 255) / 256;

    char* p = (char*)d_ws;
    size_t used = 0;
    auto carve = [&](size_t bytes) {
        char* q = p + used;
        used += (bytes + 255) & ~(size_t)255;
        return q;
    };

    // ================= tier 1: fp16-gather layout =================
    used = 0;
    float*  A    = (float*) carve((size_t)NNODE * LAT * 4);
    float*  B    = (float*) carve((size_t)NNODE * LAT * 4);
    int*    filA = (int*)   carve((size_t)RP * 4);
    int*    filT = (int*)   carve((size_t)RP * 4);
    u64*    epkA = (u64*)   carve((size_t)E ? (size_t)NNODE * CAP * 8 : 0);
    u64*    epkT = (u64*)   carve((size_t)NNODE * CAP * 8);
    __half* tf16 = (__half*)carve((size_t)ITEM * LAT * 2);
    __half* u16  = (__half*)carve((size_t)NNODE * LAT * 2);   // u16|it16
    __half* it16 = u16 + (size_t)USER * LAT;
    __half* B16  = (__half*)carve((size_t)NNODE * LAT * 2);
    __half* A16  = (__half*)epkT;              // alias: epkT dead after K2

    if (used <= ws_size && ncvt > 0) {
        // ---- K1: scatterA || scatterT || gemm(tf16) || cvt(u,it->fp16) ----
        hipMemsetAsync(filA, 0, (size_t)RP * 4 * 2, stream);   // filA|filT contig
        mega1_kernel<__half><<<ngrp * 72, 256, 0, stream>>>(
            text, W, b, tf16, ITEM,
            adj_rows, adj_cols, adj_vals, filA, epkA,
            t_rows, t_cols, t_vals, filT, epkT, E, nchunk, nscat,
            u, it, u16, it16, ncvt);

        // ---- K2: A = 0.2*spmm(t,[u16;it16]) || B = e1 = spmm(adj,[u16;tf16]) ----
        spmm_pair_kernel<__half><<<sblk * 2, 256, 0, stream>>>(
            filT, epkT, u16, it16, 0.2f, A, nullptr,
            filA, epkA, u16, tf16, 1.0f, B, B16, NNODE);

        // ---- K3: A = embeds = spmm(adj,[B16_u;it16]) + A + B ; A16 = A ----
        spmm_kernel<__half><<<sblk, 256, 0, stream>>>(
            filA, epkA, B16, it16, 1.0f, A, B, A, A16, NNODE);
        // ---- K4: B = g1 = spmm(adj, A16) ; B16 = B ----
        spmm_kernel<__half><<<sblk, 256, 0, stream>>>(
            filA, epkA, A16, A16 + (size_t)USER * LAT, 1.0f,
            nullptr, nullptr, B, B16, NNODE);
        // ---- K5: out = embeds + g1 + spmm(adj, B16) ----
        spmm_kernel<__half><<<sblk, 256, 0, stream>>>(
            filA, epkA, B16, B16 + (size_t)USER * LAT, 1.0f,
            A, B, out, nullptr, NNODE);
        return;
    }

    // ================= tier 2: fp32 layout (round-11 path) =================
    used = 0;
    float* A2    = (float*)carve((size_t)NNODE * LAT * 4);
    float* B2    = (float*)carve((size_t)NNODE * LAT * 4);
    float* tf2   = (float*)carve((size_t)ITEM * LAT * 4);
    int*   filA2 = (int*)  carve((size_t)RP * 4);
    int*   filT2 = (int*)  carve((size_t)RP * 4);
    u64*   epkA2 = (u64*)  carve((size_t)NNODE * CAP * 8);
    u64*   epkT2 = (u64*)  carve((size_t)NNODE * CAP * 8);

    if (used <= ws_size) {
        hipMemsetAsync(filA2, 0, (size_t)RP * 4 * 2, stream);
        mega1_kernel<float><<<ngrp * 72, 256, 0, stream>>>(
            text, W, b, tf2, ITEM,
            adj_rows, adj_cols, adj_vals, filA2, epkA2,
            t_rows, t_cols, t_vals, filT2, epkT2, E, nchunk, nscat,
            u, it, nullptr, nullptr, 0);

        spmm_pair_kernel<float><<<sblk * 2, 256, 0, stream>>>(
            filT2, epkT2, u, it, 0.2f, A2, nullptr,
            filA2, epkA2, u, tf2, 1.0f, B2, nullptr, NNODE);

        spmm_kernel<float><<<sblk, 256, 0, stream>>>(
            filA2, epkA2, B2, it, 1.0f, A2, B2, A2, nullptr, NNODE);
        spmm_kernel<float><<<sblk, 256, 0, stream>>>(
            filA2, epkA2, A2, A2 + (size_t)USER * LAT, 1.0f,
            nullptr, nullptr, B2, nullptr, NNODE);
        spmm_kernel<float><<<sblk, 256, 0, stream>>>(
            filA2, epkA2, B2, B2 + (size_t)USER * LAT, 1.0f,
            A2, B2, out, nullptr, NNODE);
        return;
    }

    // ================= tier 3: tiny ws, dense atomic scatter =================
    used = 0;
    float* A3  = (float*)carve((size_t)NNODE * LAT * 4);
    float* B3  = (float*)carve((size_t)NNODE * LAT * 4);
    float* tf3 = (float*)carve((size_t)ITEM * LAT * 4);
    const size_t nbuf = (size_t)NNODE * LAT * 4;
    const int ablk = (E + 3) / 4;
    const int gblk = (ITEM + 63) / 64;
    gemm_norm_kernel<<<gblk, 256, 0, stream>>>(text, W, b, tf3, ITEM);
    hipMemsetAsync(A3, 0, nbuf, stream);
    hipMemsetAsync(B3, 0, nbuf, stream);
    spmm_atomic_kernel<<<ablk, 256, 0, stream>>>(t_rows, t_cols, t_vals, 0.2f,
                                                 u, it, A3, E);
    spmm_atomic_kernel<<<ablk, 256, 0, stream>>>(adj_rows, adj_cols, adj_vals, 1.0f,
                                                 u, tf3, B3, E);
    spmm_atomic_kernel<<<ablk, 256, 0, stream>>>(adj_rows, adj_cols, adj_vals, 1.0f,
                                                 B3, it, A3, E);
    combine_kernel<<<cblk, 256, 0, stream>>>(A3, B3, out, n4);
    hipMemsetAsync(B3, 0, nbuf, stream);
    spmm_atomic_kernel<<<ablk, 256, 0, stream>>>(adj_rows, adj_cols, adj_vals, 1.0f,
                                                 A3, A3 + (size_t)USER * LAT, B3, E);
    add_kernel<<<cblk, 256, 0, stream>>>(out, B3, n4);
    hipMemsetAsync(A3, 0, nbuf, stream);
    spmm_atomic_kernel<<<ablk, 256, 0, stream>>>(adj_rows, adj_cols, adj_vals, 1.0f,
                                                 B3, B3 + (size_t)USER * LAT, A3, E);
    add_kernel<<<cblk, 256, 0, stream>>>(out, A3, n4);
}